// Round 1
// baseline (655.325 us; speedup 1.0000x reference)
//
#include <hip/hip_runtime.h>
#include <hip/hip_bf16.h>

typedef unsigned short u16;
typedef __bf16 bf16_t;
typedef bf16_t bf16x8 __attribute__((ext_vector_type(8)));
typedef float f32x4 __attribute__((ext_vector_type(4)));

// ---------------------------------------------------------------------------
// Weight fragment pre-pack: Wfrag[w][((ct*4+s)*64 + lane)*8 + i] =
//   bf16( W_w[ (32s + 8*(lane>>4) + i) * 128 + 16*ct + (lane&15) ] )
// so each lane's B-fragment for (col-tile ct, k-step s) is one contiguous
// 16B load. Same intra-lane k map is used for A, so any HW permutation of
// the per-lane k order cancels between operands.
// ---------------------------------------------------------------------------
__global__ __launch_bounds__(256) void prep_wfrag(
    const float* __restrict__ W1, const float* __restrict__ W2,
    const float* __restrict__ W3, const float* __restrict__ W4,
    u16* __restrict__ wf)
{
    int idx = blockIdx.x * 256 + threadIdx.x;      // 0 .. 65535
    const float* Ws[4] = {W1, W2, W3, W4};
    int w  = idx >> 14;
    int e  = idx & 16383;
    int i  = e & 7;
    int l  = (e >> 3) & 63;
    int s  = (e >> 9) & 3;
    int ct = (e >> 11) & 7;
    int row = 32 * s + 8 * (l >> 4) + i;
    int col = 16 * ct + (l & 15);
    float v = Ws[w][row * 128 + col];
    wf[idx] = __builtin_bit_cast(u16, (bf16_t)v);
}

// ---------------------------------------------------------------------------
// Per-node GEMM: out = epilogue( A[M,128] @ W[128,128] + b )
// One wave computes 16 rows x 128 cols via 8 col-tiles x 4 k-steps of
// mfma_f32_16x16x32_bf16. A-fragments straight from global (L1/L2-backed),
// B-fragments from the prepacked wf (L2-resident, 16B/lane loads).
// ---------------------------------------------------------------------------
enum { EP_H1 = 0, EP_L2 = 1, EP_L3 = 2, EP_L4 = 3 };

template <bool ABF16, int EP>
__global__ __launch_bounds__(256) void gemm_node(
    const void* __restrict__ Aptr,
    const u16* __restrict__ wf,
    const float* __restrict__ bias,
    const float* __restrict__ gamma,
    const float* __restrict__ beta,
    const float* __restrict__ mmean,
    const float* __restrict__ mvar,
    u16* __restrict__ obf,
    float* __restrict__ of32,
    int M)
{
    const int lane = threadIdx.x & 63;
    const int wv   = threadIdx.x >> 6;
    const int row0 = (blockIdx.x * 4 + wv) * 16;
    const int r    = lane & 15;
    const int kb   = lane >> 4;

    int arow = row0 + r;
    int arc  = arow < M ? arow : (M - 1);

    bf16x8 afrag[4];
    if (ABF16) {
        const u16* A = (const u16*)Aptr + (size_t)arc * 128 + kb * 8;
#pragma unroll
        for (int s = 0; s < 4; s++)
            afrag[s] = __builtin_bit_cast(bf16x8, *(const int4*)(A + s * 32));
    } else {
        const float* A = (const float*)Aptr + (size_t)arc * 128 + kb * 8;
#pragma unroll
        for (int s = 0; s < 4; s++) {
            float4 v0 = *(const float4*)(A + s * 32);
            float4 v1 = *(const float4*)(A + s * 32 + 4);
            bf16x8 t;
            t[0] = (bf16_t)v0.x; t[1] = (bf16_t)v0.y;
            t[2] = (bf16_t)v0.z; t[3] = (bf16_t)v0.w;
            t[4] = (bf16_t)v1.x; t[5] = (bf16_t)v1.y;
            t[6] = (bf16_t)v1.z; t[7] = (bf16_t)v1.w;
            afrag[s] = t;
        }
    }

    f32x4 acc[8];
#pragma unroll
    for (int ct = 0; ct < 8; ct++) acc[ct] = (f32x4){0.f, 0.f, 0.f, 0.f};

#pragma unroll
    for (int ct = 0; ct < 8; ct++) {
#pragma unroll
        for (int s = 0; s < 4; s++) {
            bf16x8 bfrag = __builtin_bit_cast(
                bf16x8, *(const int4*)(wf + (((ct << 2) + s) << 9) + (lane << 3)));
            acc[ct] = __builtin_amdgcn_mfma_f32_16x16x32_bf16(
                afrag[s], bfrag, acc[ct], 0, 0, 0);
        }
    }

    // C/D layout (m89-verified): col = lane&15, row = (lane>>4)*4 + j
    const int crow0 = row0 + ((lane >> 4) << 2);
    const int ccol  = lane & 15;
#pragma unroll
    for (int ct = 0; ct < 8; ct++) {
        int col  = (ct << 4) + ccol;
        float b  = bias[col];
        float scale = 1.f, shift = 0.f;
        if (EP == EP_H1 || EP == EP_L3) {
            float s_ = gamma[col] / sqrtf(mvar[col] + 1e-3f);
            scale = s_;
            shift = beta[col] - mmean[col] * s_;
        }
#pragma unroll
        for (int j = 0; j < 4; j++) {
            int row = crow0 + j;
            if (row < M) {
                float v = fmaxf(acc[ct][j] + b, 0.f);
                if (EP == EP_H1 || EP == EP_L3) v = v * scale + shift;
                size_t off = (size_t)row * 128 + col;
                if (EP == EP_H1 || EP == EP_L2 || EP == EP_L3)
                    obf[off] = __builtin_bit_cast(u16, (bf16_t)v);
                if (EP == EP_L2 || EP == EP_L3 || EP == EP_L4)
                    of32[off] = v;
            }
        }
    }
}

// ---------------------------------------------------------------------------
// GIN aggregation: agg[dst] += h[src] per edge (agg pre-initialized with the
// self term by the preceding GEMM epilogue). 128 threads per edge, 16 edges
// per block. Gathers are 256B contiguous bf16 rows (L2/L3-served).
// ---------------------------------------------------------------------------
#define AGG_EPB 16
__global__ __launch_bounds__(256) void aggregate_kernel(
    const u16* __restrict__ t, const int* __restrict__ ei,
    float* __restrict__ agg, int E)
{
    int d     = threadIdx.x & 127;
    int half  = threadIdx.x >> 7;
    int ebase = blockIdx.x * AGG_EPB + half;
#pragma unroll
    for (int j = 0; j < AGG_EPB / 2; j++) {
        int e = ebase + j * 2;
        if (e < E) {
            int src = ei[e * 2];
            int dst = ei[e * 2 + 1];
            float v = __uint_as_float(((unsigned)t[(size_t)src * 128 + d]) << 16);
            atomicAdd(agg + (size_t)dst * 128 + d, v);
        }
    }
}

// ---------------------------------------------------------------------------
// Final segment-sum over sorted `batch`: one block per group, binary-searched
// range, no atomics, full overwrite of out (no init needed).
// ---------------------------------------------------------------------------
__global__ __launch_bounds__(256) void reduce_groups(
    const float* __restrict__ h4, const int* __restrict__ batch,
    float* __restrict__ out, int N)
{
    int g    = blockIdx.x;
    int d    = threadIdx.x & 127;
    int half = threadIdx.x >> 7;

    int lo = 0, hi = N;
    while (lo < hi) { int m = (lo + hi) >> 1; if (batch[m] < g) lo = m + 1; else hi = m; }
    int start = lo;
    hi = N;
    while (lo < hi) { int m = (lo + hi) >> 1; if (batch[m] < g + 1) lo = m + 1; else hi = m; }
    int end = lo;

    float acc = 0.f;
    for (int n = start + half; n < end; n += 2)
        acc += h4[(size_t)n * 128 + d];

    __shared__ float sh[128];
    if (half) sh[d] = acc;
    __syncthreads();
    if (!half) out[g * 128 + d] = acc + sh[d];
}

// ---------------------------------------------------------------------------
extern "C" void kernel_launch(void* const* d_in, const int* in_sizes, int n_in,
                              void* d_out, int out_size, void* d_ws, size_t ws_size,
                              hipStream_t stream)
{
    const float* x   = (const float*)d_in[0];
    const int*   ei  = (const int*)d_in[1];
    const int*   bat = (const int*)d_in[2];
    const float* W1  = (const float*)d_in[3];
    const float* b1  = (const float*)d_in[4];
    const float* g1  = (const float*)d_in[5];
    const float* be1 = (const float*)d_in[6];
    const float* mm1 = (const float*)d_in[7];
    const float* mv1 = (const float*)d_in[8];
    const float* W2  = (const float*)d_in[9];
    const float* b2  = (const float*)d_in[10];
    const float* W3  = (const float*)d_in[11];
    const float* b3  = (const float*)d_in[12];
    const float* g2  = (const float*)d_in[13];
    const float* be2 = (const float*)d_in[14];
    const float* mm2 = (const float*)d_in[15];
    const float* mv2 = (const float*)d_in[16];
    const float* W4  = (const float*)d_in[17];
    const float* b4  = (const float*)d_in[18];
    float* out = (float*)d_out;

    const int N = in_sizes[0] / 128;
    const int E = in_sizes[1] / 2;
    const int G = out_size / 128;

    char* ws = (char*)d_ws;
    const size_t WF_BYTES  = 4 * 16384 * sizeof(u16);     // 128 KiB
    const size_t BF_BYTES  = (size_t)N * 128 * sizeof(u16);
    const size_t F32_BYTES = (size_t)N * 128 * sizeof(float);

    u16*   wf   = (u16*)ws;
    u16*   h1   = (u16*)(ws + WF_BYTES);                   // also holds u (layer-3 out)
    u16*   tb   = (u16*)(ws + WF_BYTES + BF_BYTES);        // layer-2 out (gather src 1)
    float* agg1 = (float*)(ws + WF_BYTES + 2 * BF_BYTES);  // also holds h4
    float* agg2 = (float*)(ws + WF_BYTES + 2 * BF_BYTES + F32_BYTES);

    prep_wfrag<<<256, 256, 0, stream>>>(W1, W2, W3, W4, wf);

    int gb = (N + 63) / 64;
    // h1 = bn1(relu(x @ W1 + b1))                         -> bf16
    gemm_node<false, EP_H1><<<gb, 256, 0, stream>>>(
        x, wf, b1, g1, be1, mm1, mv1, h1, nullptr, N);
    // t = relu(h1 @ W2 + b2)                              -> bf16 tb, f32 agg1 (self term)
    gemm_node<true, EP_L2><<<gb, 256, 0, stream>>>(
        h1, wf + 16384, b2, nullptr, nullptr, nullptr, nullptr, tb, agg1, N);
    // agg1 += scatter(t[src] -> dst)
    aggregate_kernel<<<(E + AGG_EPB - 1) / AGG_EPB, 256, 0, stream>>>(tb, ei, agg1, E);
    // u = bn2(relu(agg1 @ W3 + b3))                       -> bf16 h1, f32 agg2 (self term)
    gemm_node<false, EP_L3><<<gb, 256, 0, stream>>>(
        agg1, wf + 2 * 16384, b3, g2, be2, mm2, mv2, h1, agg2, N);
    // agg2 += scatter(u[src] -> dst)
    aggregate_kernel<<<(E + AGG_EPB - 1) / AGG_EPB, 256, 0, stream>>>(h1, ei, agg2, E);
    // h4 = relu(agg2 @ W4 + b4)                           -> f32 (reuse agg1 region)
    gemm_node<false, EP_L4><<<gb, 256, 0, stream>>>(
        agg2, wf + 3 * 16384, b4, nullptr, nullptr, nullptr, nullptr, nullptr, agg1, N);
    // out[g] = sum over nodes with batch==g
    reduce_groups<<<G, 256, 0, stream>>>(agg1, bat, out, N);
}

// Round 3
// 226.231 us; speedup vs baseline: 2.8967x; 2.8967x over previous
//
#include <hip/hip_runtime.h>
#include <hip/hip_bf16.h>

typedef unsigned short u16;
typedef __bf16 bf16_t;
typedef bf16_t bf16x8 __attribute__((ext_vector_type(8)));
typedef float f32x4 __attribute__((ext_vector_type(4)));

// ---------------------------------------------------------------------------
// Weight fragment pre-pack: one contiguous 16B load per lane per
// (col-tile, k-step) B-fragment. Same intra-lane k map as A, so any HW
// permutation of per-lane k order cancels between operands.
// ---------------------------------------------------------------------------
__global__ __launch_bounds__(256) void prep_wfrag(
    const float* __restrict__ W1, const float* __restrict__ W2,
    const float* __restrict__ W3, const float* __restrict__ W4,
    u16* __restrict__ wf)
{
    int idx = blockIdx.x * 256 + threadIdx.x;      // 0 .. 65535
    const float* Ws[4] = {W1, W2, W3, W4};
    int w  = idx >> 14;
    int e  = idx & 16383;
    int i  = e & 7;
    int l  = (e >> 3) & 63;
    int s  = (e >> 9) & 3;
    int ct = (e >> 11) & 7;
    int row = 32 * s + 8 * (l >> 4) + i;
    int col = 16 * ct + (l & 15);
    float v = Ws[w][row * 128 + col];
    wf[idx] = __builtin_bit_cast(u16, (bf16_t)v);
}

// ---------------------------------------------------------------------------
// Per-node GEMM: obf = epilogue( A[M,128] @ W[128,128] + b ), bf16 out.
// One wave: 16 rows x 128 cols via 8 col-tiles x 4 k-steps of 16x16x32 MFMA.
// ---------------------------------------------------------------------------
template <bool ABF16, bool BN>
__global__ __launch_bounds__(256) void gemm_node(
    const void* __restrict__ Aptr,
    const u16* __restrict__ wf,
    const float* __restrict__ bias,
    const float* __restrict__ gamma,
    const float* __restrict__ beta,
    const float* __restrict__ mmean,
    const float* __restrict__ mvar,
    u16* __restrict__ obf,
    int M)
{
    const int lane = threadIdx.x & 63;
    const int wv   = threadIdx.x >> 6;
    const int row0 = (blockIdx.x * 4 + wv) * 16;
    const int r    = lane & 15;
    const int kb   = lane >> 4;

    int arow = row0 + r;
    int arc  = arow < M ? arow : (M - 1);

    bf16x8 afrag[4];
    if (ABF16) {
        const u16* A = (const u16*)Aptr + (size_t)arc * 128 + kb * 8;
#pragma unroll
        for (int s = 0; s < 4; s++)
            afrag[s] = __builtin_bit_cast(bf16x8, *(const int4*)(A + s * 32));
    } else {
        const float* A = (const float*)Aptr + (size_t)arc * 128 + kb * 8;
#pragma unroll
        for (int s = 0; s < 4; s++) {
            float4 v0 = *(const float4*)(A + s * 32);
            float4 v1 = *(const float4*)(A + s * 32 + 4);
            bf16x8 t;
            t[0] = (bf16_t)v0.x; t[1] = (bf16_t)v0.y;
            t[2] = (bf16_t)v0.z; t[3] = (bf16_t)v0.w;
            t[4] = (bf16_t)v1.x; t[5] = (bf16_t)v1.y;
            t[6] = (bf16_t)v1.z; t[7] = (bf16_t)v1.w;
            afrag[s] = t;
        }
    }

    f32x4 acc[8];
#pragma unroll
    for (int ct = 0; ct < 8; ct++) acc[ct] = (f32x4){0.f, 0.f, 0.f, 0.f};

#pragma unroll
    for (int ct = 0; ct < 8; ct++) {
#pragma unroll
        for (int s = 0; s < 4; s++) {
            bf16x8 bfrag = __builtin_bit_cast(
                bf16x8, *(const int4*)(wf + (((ct << 2) + s) << 9) + (lane << 3)));
            acc[ct] = __builtin_amdgcn_mfma_f32_16x16x32_bf16(
                afrag[s], bfrag, acc[ct], 0, 0, 0);
        }
    }

    // C/D layout (m89-verified): col = lane&15, row = (lane>>4)*4 + j
    const int crow0 = row0 + ((lane >> 4) << 2);
    const int ccol  = lane & 15;
#pragma unroll
    for (int ct = 0; ct < 8; ct++) {
        int col  = (ct << 4) + ccol;
        float b  = bias[col];
        float scale = 1.f, shift = 0.f;
        if (BN) {
            float s_ = gamma[col] / sqrtf(mvar[col] + 1e-3f);
            scale = s_;
            shift = beta[col] - mmean[col] * s_;
        }
#pragma unroll
        for (int j = 0; j < 4; j++) {
            int row = crow0 + j;
            if (row < M) {
                float v = fmaxf(acc[ct][j] + b, 0.f);
                if (BN) v = v * scale + shift;
                obf[(size_t)row * 128 + col] = __builtin_bit_cast(u16, (bf16_t)v);
            }
        }
    }
}

// ---------------------------------------------------------------------------
// CSR build: zero -> deg-histogram -> exclusive scan -> slot scatter.
// ---------------------------------------------------------------------------
__global__ __launch_bounds__(256) void zero2(
    int* __restrict__ a, int* __restrict__ b, int n)
{
    int i = blockIdx.x * 256 + threadIdx.x;
    if (i < n) { a[i] = 0; b[i] = 0; }
}

__global__ __launch_bounds__(256) void hist_kernel(
    const int* __restrict__ ei, int* __restrict__ deg, int E)
{
    int e = blockIdx.x * 256 + threadIdx.x;
    if (e < E) atomicAdd(&deg[ei[2 * e + 1]], 1);
}

__global__ __launch_bounds__(256) void scan1(
    const int* __restrict__ deg, int* __restrict__ rs, int* __restrict__ bsum, int N)
{
    __shared__ int sh[256];
    int i = blockIdx.x * 256 + threadIdx.x;
    int v = (i < N) ? deg[i] : 0;
    sh[threadIdx.x] = v;
    __syncthreads();
    for (int off = 1; off < 256; off <<= 1) {
        int t = (threadIdx.x >= off) ? sh[threadIdx.x - off] : 0;
        __syncthreads();
        sh[threadIdx.x] += t;
        __syncthreads();
    }
    if (i < N) rs[i] = sh[threadIdx.x] - v;          // exclusive within block
    if (threadIdx.x == 255) bsum[blockIdx.x] = sh[255];
}

__global__ __launch_bounds__(256) void scan2(
    int* __restrict__ bsum, int nb, int* __restrict__ rs, int N, int E)
{
    __shared__ int sh[256];
    int v = (threadIdx.x < nb) ? bsum[threadIdx.x] : 0;
    sh[threadIdx.x] = v;
    __syncthreads();
    for (int off = 1; off < 256; off <<= 1) {
        int t = (threadIdx.x >= off) ? sh[threadIdx.x - off] : 0;
        __syncthreads();
        sh[threadIdx.x] += t;
        __syncthreads();
    }
    if (threadIdx.x < nb) bsum[threadIdx.x] = sh[threadIdx.x] - v;  // exclusive
    if (threadIdx.x == 0) rs[N] = E;
}

__global__ __launch_bounds__(256) void scan3(
    int* __restrict__ rs, const int* __restrict__ bsum, int N)
{
    int i = blockIdx.x * 256 + threadIdx.x;
    if (i < N) rs[i] += bsum[blockIdx.x];
}

__global__ __launch_bounds__(256) void scatter_kernel(
    const int* __restrict__ ei, const int* __restrict__ rs,
    int* __restrict__ cur, int* __restrict__ csr, int E)
{
    int e = blockIdx.x * 256 + threadIdx.x;
    if (e < E) {
        int s = ei[2 * e];
        int d = ei[2 * e + 1];
        int p = atomicAdd(&cur[d], 1);
        csr[rs[d] + p] = s;
    }
}

// ---------------------------------------------------------------------------
// GIN aggregation via CSR gather: out[n] = t[n] + sum_{s in adj(n)} t[s].
// 16 lanes per node, bf16x8 (16B) gathers, f32 register accumulation,
// one f32 row store per node. No atomics.
// ---------------------------------------------------------------------------
__global__ __launch_bounds__(256) void aggregate_csr(
    const u16* __restrict__ t, const int* __restrict__ rs,
    const int* __restrict__ csr, float* __restrict__ outf, int N)
{
    int tid  = blockIdx.x * 256 + threadIdx.x;
    int node = tid >> 4;
    if (node >= N) return;
    int d0 = (tid & 15) << 3;

    bf16x8 s8 = __builtin_bit_cast(bf16x8, *(const int4*)(t + (size_t)node * 128 + d0));
    float acc[8];
#pragma unroll
    for (int j = 0; j < 8; j++) acc[j] = (float)s8[j];

    int beg = rs[node], end = rs[node + 1];
    for (int i = beg; i < end; i++) {
        int src = csr[i];
        bf16x8 v = __builtin_bit_cast(bf16x8, *(const int4*)(t + (size_t)src * 128 + d0));
#pragma unroll
        for (int j = 0; j < 8; j++) acc[j] += (float)v[j];
    }

    float* o = outf + (size_t)node * 128 + d0;
    *(float4*)o       = make_float4(acc[0], acc[1], acc[2], acc[3]);
    *(float4*)(o + 4) = make_float4(acc[4], acc[5], acc[6], acc[7]);
}

// ---------------------------------------------------------------------------
// Final segment-sum over sorted `batch` (bf16 input): one block per group,
// binary-searched range, 16 row-groups x 16 lanes x bf16x8.
// ---------------------------------------------------------------------------
__global__ __launch_bounds__(256) void reduce_groups(
    const u16* __restrict__ h4, const int* __restrict__ batch,
    float* __restrict__ out, int N)
{
    int g = blockIdx.x;
    int lo = 0, hi = N;
    while (lo < hi) { int m = (lo + hi) >> 1; if (batch[m] < g) lo = m + 1; else hi = m; }
    int start = lo;
    hi = N;
    while (lo < hi) { int m = (lo + hi) >> 1; if (batch[m] < g + 1) lo = m + 1; else hi = m; }
    int end = lo;

    int rg = threadIdx.x >> 4;      // 0..15 row group
    int d0 = (threadIdx.x & 15) << 3;

    float acc[8];
#pragma unroll
    for (int j = 0; j < 8; j++) acc[j] = 0.f;
    for (int n = start + rg; n < end; n += 16) {
        bf16x8 v = __builtin_bit_cast(bf16x8, *(const int4*)(h4 + (size_t)n * 128 + d0));
#pragma unroll
        for (int j = 0; j < 8; j++) acc[j] += (float)v[j];
    }

    __shared__ float sh[16][128];
#pragma unroll
    for (int j = 0; j < 8; j++) sh[rg][d0 + j] = acc[j];
    __syncthreads();
    if (threadIdx.x < 128) {
        float s = 0.f;
#pragma unroll
        for (int r = 0; r < 16; r++) s += sh[r][threadIdx.x];
        out[g * 128 + threadIdx.x] = s;
    }
}

// ---------------------------------------------------------------------------
static inline size_t al256(size_t x) { return (x + 255) & ~(size_t)255; }

extern "C" void kernel_launch(void* const* d_in, const int* in_sizes, int n_in,
                              void* d_out, int out_size, void* d_ws, size_t ws_size,
                              hipStream_t stream)
{
    const float* x   = (const float*)d_in[0];
    const int*   ei  = (const int*)d_in[1];
    const int*   bat = (const int*)d_in[2];
    const float* W1  = (const float*)d_in[3];
    const float* b1  = (const float*)d_in[4];
    const float* g1  = (const float*)d_in[5];
    const float* be1 = (const float*)d_in[6];
    const float* mm1 = (const float*)d_in[7];
    const float* mv1 = (const float*)d_in[8];
    const float* W2  = (const float*)d_in[9];
    const float* b2  = (const float*)d_in[10];
    const float* W3  = (const float*)d_in[11];
    const float* b3  = (const float*)d_in[12];
    const float* g2  = (const float*)d_in[13];
    const float* be2 = (const float*)d_in[14];
    const float* mm2 = (const float*)d_in[15];
    const float* mv2 = (const float*)d_in[16];
    const float* W4  = (const float*)d_in[17];
    const float* b4  = (const float*)d_in[18];
    float* out = (float*)d_out;

    const int N = in_sizes[0] / 128;
    const int E = in_sizes[1] / 2;
    const int G = out_size / 128;
    const int nb = (N + 255) / 256;

    char* ws = (char*)d_ws;
    size_t off = 0;
    u16*   wf   = (u16*)(ws + off);  off += al256(4 * 16384 * sizeof(u16));
    u16*   h1   = (u16*)(ws + off);  off += al256((size_t)N * 128 * sizeof(u16));
    u16*   tb   = (u16*)(ws + off);  off += al256((size_t)N * 128 * sizeof(u16));
    float* aggf = (float*)(ws + off); off += al256((size_t)N * 128 * sizeof(float));
    int*   rs   = (int*)(ws + off);  off += al256((size_t)(N + 1) * sizeof(int));
    int*   deg  = (int*)(ws + off);  off += al256((size_t)N * sizeof(int));
    int*   cur  = (int*)(ws + off);  off += al256((size_t)N * sizeof(int));
    int*   bsum = (int*)(ws + off);  off += al256((size_t)nb * sizeof(int));
    int*   csr  = (int*)(ws + off);  off += al256((size_t)E * sizeof(int));

    // ---- CSR build ----
    zero2<<<nb, 256, 0, stream>>>(deg, cur, N);
    hist_kernel<<<(E + 255) / 256, 256, 0, stream>>>(ei, deg, E);
    scan1<<<nb, 256, 0, stream>>>(deg, rs, bsum, N);
    scan2<<<1, 256, 0, stream>>>(bsum, nb, rs, N, E);
    scan3<<<nb, 256, 0, stream>>>(rs, bsum, N);
    scatter_kernel<<<(E + 255) / 256, 256, 0, stream>>>(ei, rs, cur, csr, E);

    prep_wfrag<<<256, 256, 0, stream>>>(W1, W2, W3, W4, wf);

    int gb = (N + 63) / 64;
    // h1 = bn1(relu(x @ W1 + b1))
    gemm_node<false, true><<<gb, 256, 0, stream>>>(
        x, wf, b1, g1, be1, mm1, mv1, h1, N);
    // tb = relu(h1 @ W2 + b2)
    gemm_node<true, false><<<gb, 256, 0, stream>>>(
        h1, wf + 16384, b2, nullptr, nullptr, nullptr, nullptr, tb, N);
    // aggf = tb + gather(tb)
    aggregate_csr<<<(N * 16 + 255) / 256, 256, 0, stream>>>(tb, rs, csr, aggf, N);
    // h1 = bn2(relu(aggf @ W3 + b3))
    gemm_node<false, true><<<gb, 256, 0, stream>>>(
        aggf, wf + 2 * 16384, b3, g2, be2, mm2, mv2, h1, N);
    // aggf = h1 + gather(h1)
    aggregate_csr<<<(N * 16 + 255) / 256, 256, 0, stream>>>(h1, rs, csr, aggf, N);
    // tb = relu(aggf @ W4 + b4)
    gemm_node<false, false><<<gb, 256, 0, stream>>>(
        aggf, wf + 3 * 16384, b4, nullptr, nullptr, nullptr, nullptr, tb, N);
    // out[g] = sum over nodes with batch==g
    reduce_groups<<<G, 256, 0, stream>>>(tb, bat, out, N);
}

// Round 4
// 203.830 us; speedup vs baseline: 3.2151x; 1.1099x over previous
//
#include <hip/hip_runtime.h>
#include <hip/hip_bf16.h>

typedef unsigned short u16;
typedef __bf16 bf16_t;
typedef bf16_t bf16x8 __attribute__((ext_vector_type(8)));
typedef float f32x4 __attribute__((ext_vector_type(4)));

// ---------------------------------------------------------------------------
// GEMM core: one wave computes 16 rows x 128 cols of A[M,128] @ W[128,128]
// via 8 col-tiles x 4 k-steps of mfma_f32_16x16x32_bf16. A-fragments straight
// from global; B-fragments from prepacked wf (16B/lane contiguous loads).
// Same intra-lane k map for A and B, so any HW k-permutation cancels.
// ---------------------------------------------------------------------------
template <bool ABF16>
__device__ __forceinline__ void gemm_core(
    const void* __restrict__ Aptr, const u16* __restrict__ wf,
    int M, int row0, int lane, f32x4 acc[8])
{
    const int r  = lane & 15;
    const int kb = lane >> 4;
    int arow = row0 + r;
    int arc  = arow < M ? arow : (M - 1);

    bf16x8 afrag[4];
    if (ABF16) {
        const u16* A = (const u16*)Aptr + (size_t)arc * 128 + kb * 8;
#pragma unroll
        for (int s = 0; s < 4; s++)
            afrag[s] = __builtin_bit_cast(bf16x8, *(const int4*)(A + s * 32));
    } else {
        const float* A = (const float*)Aptr + (size_t)arc * 128 + kb * 8;
#pragma unroll
        for (int s = 0; s < 4; s++) {
            float4 v0 = *(const float4*)(A + s * 32);
            float4 v1 = *(const float4*)(A + s * 32 + 4);
            bf16x8 t;
            t[0] = (bf16_t)v0.x; t[1] = (bf16_t)v0.y;
            t[2] = (bf16_t)v0.z; t[3] = (bf16_t)v0.w;
            t[4] = (bf16_t)v1.x; t[5] = (bf16_t)v1.y;
            t[6] = (bf16_t)v1.z; t[7] = (bf16_t)v1.w;
            afrag[s] = t;
        }
    }

#pragma unroll
    for (int ct = 0; ct < 8; ct++) acc[ct] = (f32x4){0.f, 0.f, 0.f, 0.f};

#pragma unroll
    for (int ct = 0; ct < 8; ct++) {
#pragma unroll
        for (int s = 0; s < 4; s++) {
            bf16x8 bfrag = __builtin_bit_cast(
                bf16x8, *(const int4*)(wf + (((ct << 2) + s) << 9) + (lane << 3)));
            acc[ct] = __builtin_amdgcn_mfma_f32_16x16x32_bf16(
                afrag[s], bfrag, acc[ct], 0, 0, 0);
        }
    }
}

// Epilogue: bias + relu (+ optional BN affine), store bf16.
// C/D layout (m89-verified): col = lane&15, row = (lane>>4)*4 + j
template <bool BN>
__device__ __forceinline__ void gemm_epi_store(
    f32x4 acc[8], const float* __restrict__ bias,
    const float* __restrict__ gamma, const float* __restrict__ beta,
    const float* __restrict__ mmean, const float* __restrict__ mvar,
    u16* __restrict__ obf, int M, int row0, int lane)
{
    const int crow0 = row0 + ((lane >> 4) << 2);
    const int ccol  = lane & 15;
#pragma unroll
    for (int ct = 0; ct < 8; ct++) {
        int col  = (ct << 4) + ccol;
        float b  = bias[col];
        float scale = 1.f, shift = 0.f;
        if (BN) {
            float s_ = gamma[col] / sqrtf(mvar[col] + 1e-3f);
            scale = s_;
            shift = beta[col] - mmean[col] * s_;
        }
#pragma unroll
        for (int j = 0; j < 4; j++) {
            int row = crow0 + j;
            if (row < M) {
                float v = fmaxf(acc[ct][j] + b, 0.f);
                if (BN) v = v * scale + shift;
                obf[(size_t)row * 128 + col] = __builtin_bit_cast(u16, (bf16_t)v);
            }
        }
    }
}

// ---------------------------------------------------------------------------
// Dispatch A: zero (deg, cur, out)  ||  weight-fragment pre-pack.
//   wf[w][((ct*4+s)*64 + lane)*8 + i] = bf16(W_w[(32s+8*(lane>>4)+i)*128 + 16ct+(lane&15)])
// ---------------------------------------------------------------------------
__global__ __launch_bounds__(256) void fusedA(
    const float* __restrict__ W1, const float* __restrict__ W2,
    const float* __restrict__ W3, const float* __restrict__ W4,
    u16* __restrict__ wf, int* __restrict__ deg, int* __restrict__ cur,
    float* __restrict__ out, int N, int outsz, int nb)
{
    if ((int)blockIdx.x < nb) {
        int i = blockIdx.x * 256 + threadIdx.x;
        if (i < N) { deg[i] = 0; cur[i] = 0; }
        if (i < outsz) out[i] = 0.f;
    } else {
        int idx = (blockIdx.x - nb) * 256 + threadIdx.x;   // 0..65535
        const float* Ws[4] = {W1, W2, W3, W4};
        int w  = idx >> 14;
        int e  = idx & 16383;
        int i  = e & 7;
        int l  = (e >> 3) & 63;
        int s  = (e >> 9) & 3;
        int ct = (e >> 11) & 7;
        int row = 32 * s + 8 * (l >> 4) + i;
        int col = 16 * ct + (l & 15);
        float v = Ws[w][row * 128 + col];
        wf[idx] = __builtin_bit_cast(u16, (bf16_t)v);
    }
}

// ---------------------------------------------------------------------------
// Dispatch B: GEMM1 (x f32 -> h1 bf16, BN1)  ||  degree histogram.
// ---------------------------------------------------------------------------
__global__ __launch_bounds__(256) void fusedB(
    const float* __restrict__ x, const u16* __restrict__ wf,
    const float* __restrict__ b1, const float* __restrict__ g1,
    const float* __restrict__ be1, const float* __restrict__ mm1,
    const float* __restrict__ mv1, u16* __restrict__ h1, int M,
    const int* __restrict__ ei, int* __restrict__ deg, int E, int gb)
{
    if ((int)blockIdx.x < gb) {
        int lane = threadIdx.x & 63, wv = threadIdx.x >> 6;
        int row0 = (blockIdx.x * 4 + wv) * 16;
        f32x4 acc[8];
        gemm_core<false>(x, wf, M, row0, lane, acc);
        gemm_epi_store<true>(acc, b1, g1, be1, mm1, mv1, h1, M, row0, lane);
    } else {
        int e = (blockIdx.x - gb) * 256 + threadIdx.x;
        if (e < E) atomicAdd(&deg[ei[2 * e + 1]], 1);
    }
}

// ---------------------------------------------------------------------------
// Dispatch C: GEMM2 (h1 -> tb, no BN)  ||  scan1 (block-local exclusive scan
// of deg into rs, block sums into bsum).
// ---------------------------------------------------------------------------
__global__ __launch_bounds__(256) void fusedC(
    const u16* __restrict__ h1, const u16* __restrict__ wf,
    const float* __restrict__ b2, u16* __restrict__ tb, int M,
    const int* __restrict__ deg, int* __restrict__ rs, int* __restrict__ bsum,
    int N, int gb)
{
    if ((int)blockIdx.x < gb) {
        int lane = threadIdx.x & 63, wv = threadIdx.x >> 6;
        int row0 = (blockIdx.x * 4 + wv) * 16;
        f32x4 acc[8];
        gemm_core<true>(h1, wf, M, row0, lane, acc);
        gemm_epi_store<false>(acc, b2, nullptr, nullptr, nullptr, nullptr,
                              tb, M, row0, lane);
    } else {
        __shared__ int sh[256];
        int blk = blockIdx.x - gb;
        int i = blk * 256 + threadIdx.x;
        int v = (i < N) ? deg[i] : 0;
        sh[threadIdx.x] = v;
        __syncthreads();
        for (int off = 1; off < 256; off <<= 1) {
            int t = (threadIdx.x >= off) ? sh[threadIdx.x - off] : 0;
            __syncthreads();
            sh[threadIdx.x] += t;
            __syncthreads();
        }
        if (i < N) rs[i] = sh[threadIdx.x] - v;          // block-local exclusive
        if (threadIdx.x == 255) bsum[blk] = sh[255];
    }
}

// Dispatch D: exclusivize bsum (nb <= 256, one block).
__global__ __launch_bounds__(256) void scan2k(int* __restrict__ bsum, int nb)
{
    __shared__ int sh[256];
    int v = (threadIdx.x < nb) ? bsum[threadIdx.x] : 0;
    sh[threadIdx.x] = v;
    __syncthreads();
    for (int off = 1; off < 256; off <<= 1) {
        int t = (threadIdx.x >= off) ? sh[threadIdx.x - off] : 0;
        __syncthreads();
        sh[threadIdx.x] += t;
        __syncthreads();
    }
    if (threadIdx.x < nb) bsum[threadIdx.x] = sh[threadIdx.x] - v;
}

// Dispatch E: scatter edges into CSR slots (scan3 folded: base = rs + bsum).
__global__ __launch_bounds__(256) void scatterk(
    const int* __restrict__ ei, const int* __restrict__ rs,
    const int* __restrict__ bsum, int* __restrict__ cur,
    int* __restrict__ csr, int E)
{
    int e = blockIdx.x * 256 + threadIdx.x;
    if (e < E) {
        int s = ei[2 * e];
        int d = ei[2 * e + 1];
        int p = atomicAdd(&cur[d], 1);
        csr[rs[d] + bsum[d >> 8] + p] = s;
    }
}

// ---------------------------------------------------------------------------
// Dispatches F/H: GIN aggregation, CSR gather, bf16 in -> bf16 out.
// 16 lanes per node, 16B gathers, f32 accumulation, 2-way unrolled to keep
// two gathers in flight.
// ---------------------------------------------------------------------------
__global__ __launch_bounds__(256) void aggk(
    const u16* __restrict__ t, const int* __restrict__ rs,
    const int* __restrict__ bsum, const int* __restrict__ csr,
    u16* __restrict__ ob, int N, int E)
{
    int tid  = blockIdx.x * 256 + threadIdx.x;
    int node = tid >> 4;
    if (node >= N) return;
    int d0 = (tid & 15) << 3;

    bf16x8 s8 = __builtin_bit_cast(bf16x8, *(const int4*)(t + (size_t)node * 128 + d0));
    float acc[8];
#pragma unroll
    for (int j = 0; j < 8; j++) acc[j] = (float)s8[j];

    int beg = rs[node] + bsum[node >> 8];
    int end = (node + 1 < N) ? rs[node + 1] + bsum[(node + 1) >> 8] : E;

    int i = beg;
    for (; i + 1 < end; i += 2) {
        int src0 = csr[i];
        int src1 = csr[i + 1];
        bf16x8 v0 = __builtin_bit_cast(bf16x8, *(const int4*)(t + (size_t)src0 * 128 + d0));
        bf16x8 v1 = __builtin_bit_cast(bf16x8, *(const int4*)(t + (size_t)src1 * 128 + d0));
#pragma unroll
        for (int j = 0; j < 8; j++) acc[j] += (float)v0[j];
#pragma unroll
        for (int j = 0; j < 8; j++) acc[j] += (float)v1[j];
    }
    if (i < end) {
        int src = csr[i];
        bf16x8 v = __builtin_bit_cast(bf16x8, *(const int4*)(t + (size_t)src * 128 + d0));
#pragma unroll
        for (int j = 0; j < 8; j++) acc[j] += (float)v[j];
    }

    bf16x8 o;
#pragma unroll
    for (int j = 0; j < 8; j++) o[j] = (bf16_t)acc[j];
    *(int4*)(ob + (size_t)node * 128 + d0) = __builtin_bit_cast(int4, o);
}

// ---------------------------------------------------------------------------
// Dispatch G: GEMM3 (aggb -> h1, BN2).
// ---------------------------------------------------------------------------
__global__ __launch_bounds__(256) void gemm3k(
    const u16* __restrict__ A, const u16* __restrict__ wf,
    const float* __restrict__ b3, const float* __restrict__ g2,
    const float* __restrict__ be2, const float* __restrict__ mm2,
    const float* __restrict__ mv2, u16* __restrict__ ob, int M)
{
    int lane = threadIdx.x & 63, wv = threadIdx.x >> 6;
    int row0 = (blockIdx.x * 4 + wv) * 16;
    f32x4 acc[8];
    gemm_core<true>(A, wf, M, row0, lane, acc);
    gemm_epi_store<true>(acc, b3, g2, be2, mm2, mv2, ob, M, row0, lane);
}

// ---------------------------------------------------------------------------
// Dispatch I: GEMM4 + fused group reduction. batch is sorted, so each lane's
// 4 consecutive rows form >=1 group runs; one atomicAdd per run per col.
// out must be zeroed (dispatch A does it).
// ---------------------------------------------------------------------------
__global__ __launch_bounds__(256) void gemm4red(
    const u16* __restrict__ A, const u16* __restrict__ wf,
    const float* __restrict__ b4, const int* __restrict__ batch,
    float* __restrict__ out, int M)
{
    int lane = threadIdx.x & 63, wv = threadIdx.x >> 6;
    int row0 = (blockIdx.x * 4 + wv) * 16;
    f32x4 acc[8];
    gemm_core<true>(A, wf, M, row0, lane, acc);

    const int crow0 = row0 + ((lane >> 4) << 2);
    const int ccol  = lane & 15;
    int bj[4];
#pragma unroll
    for (int j = 0; j < 4; j++) {
        int row = crow0 + j;
        bj[j] = (row < M) ? batch[row] : -1;
    }
#pragma unroll
    for (int ct = 0; ct < 8; ct++) {
        int col = (ct << 4) + ccol;
        float b = b4[col];
        float run = 0.f;
        int gp = -1;
#pragma unroll
        for (int j = 0; j < 4; j++) {
            if (bj[j] < 0) continue;
            float v = fmaxf(acc[ct][j] + b, 0.f);
            if (bj[j] != gp) {
                if (gp >= 0) atomicAdd(out + gp * 128 + col, run);
                run = 0.f;
                gp  = bj[j];
            }
            run += v;
        }
        if (gp >= 0) atomicAdd(out + gp * 128 + col, run);
    }
}

// ---------------------------------------------------------------------------
static inline size_t al256(size_t x) { return (x + 255) & ~(size_t)255; }

extern "C" void kernel_launch(void* const* d_in, const int* in_sizes, int n_in,
                              void* d_out, int out_size, void* d_ws, size_t ws_size,
                              hipStream_t stream)
{
    const float* x   = (const float*)d_in[0];
    const int*   ei  = (const int*)d_in[1];
    const int*   bat = (const int*)d_in[2];
    const float* W1  = (const float*)d_in[3];
    const float* b1  = (const float*)d_in[4];
    const float* g1  = (const float*)d_in[5];
    const float* be1 = (const float*)d_in[6];
    const float* mm1 = (const float*)d_in[7];
    const float* mv1 = (const float*)d_in[8];
    const float* W2  = (const float*)d_in[9];
    const float* b2  = (const float*)d_in[10];
    const float* W3  = (const float*)d_in[11];
    const float* b3  = (const float*)d_in[12];
    const float* g2  = (const float*)d_in[13];
    const float* be2 = (const float*)d_in[14];
    const float* mm2 = (const float*)d_in[15];
    const float* mv2 = (const float*)d_in[16];
    const float* W4  = (const float*)d_in[17];
    const float* b4  = (const float*)d_in[18];
    float* out = (float*)d_out;

    const int N  = in_sizes[0] / 128;
    const int E  = in_sizes[1] / 2;
    const int nb = (N + 255) / 256;
    const int eb = (E + 255) / 256;
    const int gb = (N + 63) / 64;

    char* ws = (char*)d_ws;
    size_t off = 0;
    u16*   wf   = (u16*)(ws + off);  off += al256(4 * 16384 * sizeof(u16));
    u16*   h1   = (u16*)(ws + off);  off += al256((size_t)N * 128 * sizeof(u16));
    u16*   tb   = (u16*)(ws + off);  off += al256((size_t)N * 128 * sizeof(u16));
    u16*   aggb = (u16*)(ws + off);  off += al256((size_t)N * 128 * sizeof(u16));
    int*   rs   = (int*)(ws + off);  off += al256((size_t)N * sizeof(int));
    int*   deg  = (int*)(ws + off);  off += al256((size_t)N * sizeof(int));
    int*   cur  = (int*)(ws + off);  off += al256((size_t)N * sizeof(int));
    int*   bsum = (int*)(ws + off);  off += al256((size_t)nb * sizeof(int));
    int*   csr  = (int*)(ws + off);  off += al256((size_t)E * sizeof(int));

    // A: zero(deg,cur,out) || wfrag pack
    fusedA<<<nb + 256, 256, 0, stream>>>(W1, W2, W3, W4, wf, deg, cur, out,
                                         N, out_size, nb);
    // B: GEMM1 || hist
    fusedB<<<gb + eb, 256, 0, stream>>>(x, wf, b1, g1, be1, mm1, mv1, h1, N,
                                        ei, deg, E, gb);
    // C: GEMM2 || scan1
    fusedC<<<gb + nb, 256, 0, stream>>>(h1, wf + 16384, b2, tb, N,
                                        deg, rs, bsum, N, gb);
    // D: scan bsum
    scan2k<<<1, 256, 0, stream>>>(bsum, nb);
    // E: scatter into CSR
    scatterk<<<eb, 256, 0, stream>>>(ei, rs, bsum, cur, csr, E);
    // F: aggb = tb + gather(tb)
    aggk<<<(N * 16 + 255) / 256, 256, 0, stream>>>(tb, rs, bsum, csr, aggb, N, E);
    // G: h1 = bn2(relu(aggb @ W3 + b3))
    gemm3k<<<gb, 256, 0, stream>>>(aggb, wf + 2 * 16384, b3, g2, be2, mm2, mv2,
                                   h1, N);
    // H: tb = h1 + gather(h1)
    aggk<<<(N * 16 + 255) / 256, 256, 0, stream>>>(h1, rs, bsum, csr, tb, N, E);
    // I: out += group-reduced relu(tb @ W4 + b4)
    gemm4red<<<gb, 256, 0, stream>>>(tb, wf + 3 * 16384, b4, bat, out, N);
}

// Round 5
// 187.419 us; speedup vs baseline: 3.4966x; 1.0876x over previous
//
#include <hip/hip_runtime.h>
#include <hip/hip_bf16.h>

typedef unsigned short u16;
typedef __bf16 bf16_t;
typedef bf16_t bf16x8 __attribute__((ext_vector_type(8)));
typedef float f32x4 __attribute__((ext_vector_type(4)));

// ---------------------------------------------------------------------------
// GEMM core (global A): one wave computes 16 rows x 128 cols of
// A[M,128] @ W[128,128] via 8 col-tiles x 4 k-steps of mfma_f32_16x16x32_bf16.
// B-fragments from prepacked wf (16B/lane contiguous). Same intra-lane k map
// for A and B, so any HW k-permutation cancels.
// ---------------------------------------------------------------------------
template <bool ABF16>
__device__ __forceinline__ void gemm_core(
    const void* __restrict__ Aptr, const u16* __restrict__ wf,
    int M, int row0, int lane, f32x4 acc[8])
{
    const int r  = lane & 15;
    const int kb = lane >> 4;
    int arow = row0 + r;
    int arc  = arow < M ? arow : (M - 1);

    bf16x8 afrag[4];
    if (ABF16) {
        const u16* A = (const u16*)Aptr + (size_t)arc * 128 + kb * 8;
#pragma unroll
        for (int s = 0; s < 4; s++)
            afrag[s] = __builtin_bit_cast(bf16x8, *(const int4*)(A + s * 32));
    } else {
        const float* A = (const float*)Aptr + (size_t)arc * 128 + kb * 8;
#pragma unroll
        for (int s = 0; s < 4; s++) {
            float4 v0 = *(const float4*)(A + s * 32);
            float4 v1 = *(const float4*)(A + s * 32 + 4);
            bf16x8 t;
            t[0] = (bf16_t)v0.x; t[1] = (bf16_t)v0.y;
            t[2] = (bf16_t)v0.z; t[3] = (bf16_t)v0.w;
            t[4] = (bf16_t)v1.x; t[5] = (bf16_t)v1.y;
            t[6] = (bf16_t)v1.z; t[7] = (bf16_t)v1.w;
            afrag[s] = t;
        }
    }

#pragma unroll
    for (int ct = 0; ct < 8; ct++) acc[ct] = (f32x4){0.f, 0.f, 0.f, 0.f};

#pragma unroll
    for (int ct = 0; ct < 8; ct++) {
#pragma unroll
        for (int s = 0; s < 4; s++) {
            bf16x8 bfrag = __builtin_bit_cast(
                bf16x8, *(const int4*)(wf + (((ct << 2) + s) << 9) + (lane << 3)));
            acc[ct] = __builtin_amdgcn_mfma_f32_16x16x32_bf16(
                afrag[s], bfrag, acc[ct], 0, 0, 0);
        }
    }
}

// Epilogue: bias + relu (+ optional BN affine), store bf16.
// C/D layout (m89-verified): col = lane&15, row = (lane>>4)*4 + j
template <bool BN>
__device__ __forceinline__ void gemm_epi_store(
    f32x4 acc[8], const float* __restrict__ bias,
    const float* __restrict__ gamma, const float* __restrict__ beta,
    const float* __restrict__ mmean, const float* __restrict__ mvar,
    u16* __restrict__ obf, int M, int row0, int lane)
{
    const int crow0 = row0 + ((lane >> 4) << 2);
    const int ccol  = lane & 15;
#pragma unroll
    for (int ct = 0; ct < 8; ct++) {
        int col  = (ct << 4) + ccol;
        float b  = bias[col];
        float scale = 1.f, shift = 0.f;
        if (BN) {
            float s_ = gamma[col] / sqrtf(mvar[col] + 1e-3f);
            scale = s_;
            shift = beta[col] - mmean[col] * s_;
        }
#pragma unroll
        for (int j = 0; j < 4; j++) {
            int row = crow0 + j;
            if (row < M) {
                float v = fmaxf(acc[ct][j] + b, 0.f);
                if (BN) v = v * scale + shift;
                obf[(size_t)row * 128 + col] = __builtin_bit_cast(u16, (bf16_t)v);
            }
        }
    }
}

// Block-local exclusive scan of bsum[0..nb) into sb (nb <= 256). All threads
// participate (internal barriers).
__device__ __forceinline__ void scan_bsum(
    const int* __restrict__ bsum, int nb, int* sb)
{
    int v = (threadIdx.x < (unsigned)nb) ? bsum[threadIdx.x] : 0;
    sb[threadIdx.x] = v;
    __syncthreads();
    for (int off = 1; off < 256; off <<= 1) {
        int t = (threadIdx.x >= (unsigned)off) ? sb[threadIdx.x - off] : 0;
        __syncthreads();
        sb[threadIdx.x] += t;
        __syncthreads();
    }
    int inc = sb[threadIdx.x];
    __syncthreads();
    sb[threadIdx.x] = inc - v;          // exclusive
    __syncthreads();
}

// ---------------------------------------------------------------------------
// Dispatch A: zero (deg, cur, out)  ||  weight-fragment pre-pack.
// ---------------------------------------------------------------------------
__global__ __launch_bounds__(256) void fusedA(
    const float* __restrict__ W1, const float* __restrict__ W2,
    const float* __restrict__ W3, const float* __restrict__ W4,
    u16* __restrict__ wf, int* __restrict__ deg, int* __restrict__ cur,
    float* __restrict__ out, int N, int outsz, int nb)
{
    if ((int)blockIdx.x < nb) {
        int i = blockIdx.x * 256 + threadIdx.x;
        if (i < N) { deg[i] = 0; cur[i] = 0; }
        if (i < outsz) out[i] = 0.f;
    } else {
        int idx = (blockIdx.x - nb) * 256 + threadIdx.x;   // 0..65535
        const float* Ws[4] = {W1, W2, W3, W4};
        int w  = idx >> 14;
        int e  = idx & 16383;
        int i  = e & 7;
        int l  = (e >> 3) & 63;
        int s  = (e >> 9) & 3;
        int ct = (e >> 11) & 7;
        int row = 32 * s + 8 * (l >> 4) + i;
        int col = 16 * ct + (l & 15);
        float v = Ws[w][row * 128 + col];
        wf[idx] = __builtin_bit_cast(u16, (bf16_t)v);
    }
}

// ---------------------------------------------------------------------------
// Dispatch B: GEMM1 (x f32 -> h1 bf16, BN1)  ||  degree histogram.
// ---------------------------------------------------------------------------
__global__ __launch_bounds__(256) void fusedB(
    const float* __restrict__ x, const u16* __restrict__ wf,
    const float* __restrict__ b1, const float* __restrict__ g1,
    const float* __restrict__ be1, const float* __restrict__ mm1,
    const float* __restrict__ mv1, u16* __restrict__ h1, int M,
    const int* __restrict__ ei, int* __restrict__ deg, int E, int gb)
{
    if ((int)blockIdx.x < gb) {
        int lane = threadIdx.x & 63, wv = threadIdx.x >> 6;
        int row0 = (blockIdx.x * 4 + wv) * 16;
        f32x4 acc[8];
        gemm_core<false>(x, wf, M, row0, lane, acc);
        gemm_epi_store<true>(acc, b1, g1, be1, mm1, mv1, h1, M, row0, lane);
    } else {
        int e = (blockIdx.x - gb) * 256 + threadIdx.x;
        if (e < E) atomicAdd(&deg[ei[2 * e + 1]], 1);
    }
}

// ---------------------------------------------------------------------------
// Dispatch C: GEMM2 (h1 -> tb, no BN)  ||  scan1 (block-local exclusive scan
// of deg into rs, block sums into bsum).
// ---------------------------------------------------------------------------
__global__ __launch_bounds__(256) void fusedC(
    const u16* __restrict__ h1, const u16* __restrict__ wf,
    const float* __restrict__ b2, u16* __restrict__ tb, int M,
    const int* __restrict__ deg, int* __restrict__ rs, int* __restrict__ bsum,
    int N, int gb)
{
    if ((int)blockIdx.x < gb) {
        int lane = threadIdx.x & 63, wv = threadIdx.x >> 6;
        int row0 = (blockIdx.x * 4 + wv) * 16;
        f32x4 acc[8];
        gemm_core<true>(h1, wf, M, row0, lane, acc);
        gemm_epi_store<false>(acc, b2, nullptr, nullptr, nullptr, nullptr,
                              tb, M, row0, lane);
    } else {
        __shared__ int sh[256];
        int blk = blockIdx.x - gb;
        int i = blk * 256 + threadIdx.x;
        int v = (i < N) ? deg[i] : 0;
        sh[threadIdx.x] = v;
        __syncthreads();
        for (int off = 1; off < 256; off <<= 1) {
            int t = (threadIdx.x >= (unsigned)off) ? sh[threadIdx.x - off] : 0;
            __syncthreads();
            sh[threadIdx.x] += t;
            __syncthreads();
        }
        if (i < N) rs[i] = sh[threadIdx.x] - v;          // block-local exclusive
        if (threadIdx.x == 255) bsum[blk] = sh[255];
    }
}

// ---------------------------------------------------------------------------
// Dispatch D: scatter edges into CSR slots. Per-block redundant scan of bsum
// (folds old scan2/scan3 dispatches).
// ---------------------------------------------------------------------------
__global__ __launch_bounds__(256) void scatterk(
    const int* __restrict__ ei, const int* __restrict__ rs,
    const int* __restrict__ bsum, int* __restrict__ cur,
    int* __restrict__ csr, int E, int nb)
{
    __shared__ int sb[256];
    scan_bsum(bsum, nb, sb);
    int e = blockIdx.x * 256 + threadIdx.x;
    if (e < E) {
        int s = ei[2 * e];
        int d = ei[2 * e + 1];
        int p = atomicAdd(&cur[d], 1);
        csr[rs[d] + sb[d >> 8] + p] = s;
    }
}

// ---------------------------------------------------------------------------
// Dispatches E/F: fused GIN-aggregate + GEMM.
// Phase 1: block gathers its 64 rows' neighborhoods (self + CSR neighbors)
//   into an XOR-swizzled LDS A-tile: byte = rl*256 + ((c ^ (rl&7)) << 4).
//   Both the 16B writes and the b128 fragment reads land 2-way per bank (free).
// Phase 2: MFMA from LDS.
// Epilogue: BN store (gemm3) or LDS-staged group reduction (gemm4):
//   a block's 64 sorted rows span few groups -> accumulate into grp LDS via
//   LDS atomics, flush span*128 global atomics (vs 32/lane direct).
// ---------------------------------------------------------------------------
template <bool BN_, bool RED>
__global__ __launch_bounds__(256) void aggGemm(
    const u16* __restrict__ t, const int* __restrict__ rs,
    const int* __restrict__ bsum, const int* __restrict__ csr,
    const u16* __restrict__ wf, const float* __restrict__ bias,
    const float* __restrict__ gamma, const float* __restrict__ beta,
    const float* __restrict__ mmean, const float* __restrict__ mvar,
    u16* __restrict__ obf, const int* __restrict__ batch,
    float* __restrict__ out, int N, int E, int nb)
{
    constexpr int GSPAN = 20;
    __shared__ u16 ldsA[64 * 128];
    __shared__ int sb[256];
    __shared__ float grp[RED ? (GSPAN * 128) : 1];

    scan_bsum(bsum, nb, sb);

    const int row0blk = blockIdx.x * 64;
    const int sub = threadIdx.x >> 4;       // 0..15: node within pass
    const int c   = threadIdx.x & 15;       // 16B chunk within row

#pragma unroll
    for (int pass = 0; pass < 4; pass++) {
        int rl   = pass * 16 + sub;         // 0..63 local row
        int node = row0blk + rl;
        float acc[8];
        if (node < N) {
            bf16x8 s8 = __builtin_bit_cast(
                bf16x8, *(const int4*)(t + (size_t)node * 128 + c * 8));
#pragma unroll
            for (int j = 0; j < 8; j++) acc[j] = (float)s8[j];

            int beg = rs[node] + sb[node >> 8];
            int end = (node + 1 < N) ? rs[node + 1] + sb[(node + 1) >> 8] : E;
            int i = beg;
            for (; i + 1 < end; i += 2) {
                int src0 = csr[i];
                int src1 = csr[i + 1];
                bf16x8 v0 = __builtin_bit_cast(
                    bf16x8, *(const int4*)(t + (size_t)src0 * 128 + c * 8));
                bf16x8 v1 = __builtin_bit_cast(
                    bf16x8, *(const int4*)(t + (size_t)src1 * 128 + c * 8));
#pragma unroll
                for (int j = 0; j < 8; j++) acc[j] += (float)v0[j];
#pragma unroll
                for (int j = 0; j < 8; j++) acc[j] += (float)v1[j];
            }
            if (i < end) {
                int src = csr[i];
                bf16x8 v = __builtin_bit_cast(
                    bf16x8, *(const int4*)(t + (size_t)src * 128 + c * 8));
#pragma unroll
                for (int j = 0; j < 8; j++) acc[j] += (float)v[j];
            }
        } else {
#pragma unroll
            for (int j = 0; j < 8; j++) acc[j] = 0.f;
        }
        bf16x8 o;
#pragma unroll
        for (int j = 0; j < 8; j++) o[j] = (bf16_t)acc[j];
        *(int4*)((char*)ldsA + rl * 256 + ((c ^ (rl & 7)) << 4)) =
            __builtin_bit_cast(int4, o);
    }

    if (RED) {
        for (int i = threadIdx.x; i < GSPAN * 128; i += 256) grp[i] = 0.f;
    }
    __syncthreads();

    // ---- GEMM from swizzled LDS ----
    const int lane = threadIdx.x & 63;
    const int wv   = threadIdx.x >> 6;
    const int r    = lane & 15;
    const int kb   = lane >> 4;
    const int rl   = wv * 16 + r;

    bf16x8 afrag[4];
#pragma unroll
    for (int s = 0; s < 4; s++)
        afrag[s] = __builtin_bit_cast(
            bf16x8, *(const int4*)((const char*)ldsA + rl * 256 +
                                   ((((s << 2) + kb) ^ (rl & 7)) << 4)));

    f32x4 acc[8];
#pragma unroll
    for (int ct = 0; ct < 8; ct++) acc[ct] = (f32x4){0.f, 0.f, 0.f, 0.f};
#pragma unroll
    for (int ct = 0; ct < 8; ct++) {
#pragma unroll
        for (int s = 0; s < 4; s++) {
            bf16x8 bfrag = __builtin_bit_cast(
                bf16x8, *(const int4*)(wf + (((ct << 2) + s) << 9) + (lane << 3)));
            acc[ct] = __builtin_amdgcn_mfma_f32_16x16x32_bf16(
                afrag[s], bfrag, acc[ct], 0, 0, 0);
        }
    }

    const int row0 = row0blk + wv * 16;
    if constexpr (!RED) {
        gemm_epi_store<BN_>(acc, bias, gamma, beta, mmean, mvar, obf, N, row0, lane);
    } else {
        int gfirst = batch[row0blk];
        int lastr  = row0blk + 63 < N - 1 ? row0blk + 63 : N - 1;
        int glast  = batch[lastr];
        const int crow0 = row0 + ((lane >> 4) << 2);
        const int ccol  = lane & 15;
        int bj[4];
#pragma unroll
        for (int j = 0; j < 4; j++) {
            int row = crow0 + j;
            bj[j] = (row < N) ? batch[row] : -1;
        }
        if (glast - gfirst < GSPAN) {
#pragma unroll
            for (int ct = 0; ct < 8; ct++) {
                int col = (ct << 4) + ccol;
                float b = bias[col];
                float run = 0.f;
                int gp = -1;
#pragma unroll
                for (int j = 0; j < 4; j++) {
                    if (bj[j] < 0) continue;
                    float v = fmaxf(acc[ct][j] + b, 0.f);
                    if (bj[j] != gp) {
                        if (gp >= 0) atomicAdd(&grp[(gp - gfirst) * 128 + col], run);
                        run = 0.f;
                        gp  = bj[j];
                    }
                    run += v;
                }
                if (gp >= 0) atomicAdd(&grp[(gp - gfirst) * 128 + col], run);
            }
            __syncthreads();
            int span = glast - gfirst + 1;
            for (int i = threadIdx.x; i < span * 128; i += 256) {
                float v = grp[i];
                if (v != 0.f) atomicAdd(out + (size_t)gfirst * 128 + i, v);
            }
        } else {
            // pathological tiny-group fallback: direct global atomics
#pragma unroll
            for (int ct = 0; ct < 8; ct++) {
                int col = (ct << 4) + ccol;
                float b = bias[col];
                float run = 0.f;
                int gp = -1;
#pragma unroll
                for (int j = 0; j < 4; j++) {
                    if (bj[j] < 0) continue;
                    float v = fmaxf(acc[ct][j] + b, 0.f);
                    if (bj[j] != gp) {
                        if (gp >= 0) atomicAdd(out + (size_t)gp * 128 + col, run);
                        run = 0.f;
                        gp  = bj[j];
                    }
                    run += v;
                }
                if (gp >= 0) atomicAdd(out + (size_t)gp * 128 + col, run);
            }
        }
    }
}

// ---------------------------------------------------------------------------
static inline size_t al256(size_t x) { return (x + 255) & ~(size_t)255; }

extern "C" void kernel_launch(void* const* d_in, const int* in_sizes, int n_in,
                              void* d_out, int out_size, void* d_ws, size_t ws_size,
                              hipStream_t stream)
{
    const float* x   = (const float*)d_in[0];
    const int*   ei  = (const int*)d_in[1];
    const int*   bat = (const int*)d_in[2];
    const float* W1  = (const float*)d_in[3];
    const float* b1  = (const float*)d_in[4];
    const float* g1  = (const float*)d_in[5];
    const float* be1 = (const float*)d_in[6];
    const float* mm1 = (const float*)d_in[7];
    const float* mv1 = (const float*)d_in[8];
    const float* W2  = (const float*)d_in[9];
    const float* b2  = (const float*)d_in[10];
    const float* W3  = (const float*)d_in[11];
    const float* b3  = (const float*)d_in[12];
    const float* g2  = (const float*)d_in[13];
    const float* be2 = (const float*)d_in[14];
    const float* mm2 = (const float*)d_in[15];
    const float* mv2 = (const float*)d_in[16];
    const float* W4  = (const float*)d_in[17];
    const float* b4  = (const float*)d_in[18];
    float* out = (float*)d_out;

    const int N  = in_sizes[0] / 128;
    const int E  = in_sizes[1] / 2;
    const int nb = (N + 255) / 256;
    const int eb = (E + 255) / 256;
    const int gb = (N + 63) / 64;

    char* ws = (char*)d_ws;
    size_t off = 0;
    u16*   wf   = (u16*)(ws + off);  off += al256(4 * 16384 * sizeof(u16));
    u16*   h1   = (u16*)(ws + off);  off += al256((size_t)N * 128 * sizeof(u16));
    u16*   tb   = (u16*)(ws + off);  off += al256((size_t)N * 128 * sizeof(u16));
    int*   rs   = (int*)(ws + off);  off += al256((size_t)N * sizeof(int));
    int*   deg  = (int*)(ws + off);  off += al256((size_t)N * sizeof(int));
    int*   cur  = (int*)(ws + off);  off += al256((size_t)N * sizeof(int));
    int*   bsum = (int*)(ws + off);  off += al256((size_t)nb * sizeof(int));
    int*   csr  = (int*)(ws + off);  off += al256((size_t)E * sizeof(int));

    // A: zero(deg,cur,out) || wfrag pack
    fusedA<<<nb + 256, 256, 0, stream>>>(W1, W2, W3, W4, wf, deg, cur, out,
                                         N, out_size, nb);
    // B: GEMM1 || hist
    fusedB<<<gb + eb, 256, 0, stream>>>(x, wf, b1, g1, be1, mm1, mv1, h1, N,
                                        ei, deg, E, gb);
    // C: GEMM2 || scan1
    fusedC<<<gb + nb, 256, 0, stream>>>(h1, wf + 16384, b2, tb, N,
                                        deg, rs, bsum, N, gb);
    // D: scatter into CSR (scan folded per-block)
    scatterk<<<eb, 256, 0, stream>>>(ei, rs, bsum, cur, csr, E, nb);
    // E: h1 = bn2(relu( (tb + gather(tb)) @ W3 + b3 ))
    aggGemm<true, false><<<gb, 256, 0, stream>>>(
        tb, rs, bsum, csr, wf + 2 * 16384, b3, g2, be2, mm2, mv2,
        h1, nullptr, nullptr, N, E, nb);
    // F: out += group-reduce relu( (h1 + gather(h1)) @ W4 + b4 )
    aggGemm<false, true><<<gb, 256, 0, stream>>>(
        h1, rs, bsum, csr, wf + 3 * 16384, b4, nullptr, nullptr, nullptr, nullptr,
        nullptr, bat, out, N, E, nb);
}

// Round 6
// 171.542 us; speedup vs baseline: 3.8202x; 1.0926x over previous
//
#include <hip/hip_runtime.h>
#include <hip/hip_bf16.h>

typedef unsigned short u16;
typedef __bf16 bf16_t;
typedef bf16_t bf16x8 __attribute__((ext_vector_type(8)));
typedef float f32x4 __attribute__((ext_vector_type(4)));

// ---------------------------------------------------------------------------
// GEMM core (global A): one wave computes 16 rows x 128 cols of
// A[M,128] @ W[128,128] via 8 col-tiles x 4 k-steps of mfma_f32_16x16x32_bf16.
// B-fragments from prepacked wf (16B/lane contiguous). Same intra-lane k map
// for A and B, so any HW k-permutation cancels.
// ---------------------------------------------------------------------------
template <bool ABF16>
__device__ __forceinline__ void gemm_core(
    const void* __restrict__ Aptr, const u16* __restrict__ wf,
    int M, int row0, int lane, f32x4 acc[8])
{
    const int r  = lane & 15;
    const int kb = lane >> 4;
    int arow = row0 + r;
    int arc  = arow < M ? arow : (M - 1);

    bf16x8 afrag[4];
    if (ABF16) {
        const u16* A = (const u16*)Aptr + (size_t)arc * 128 + kb * 8;
#pragma unroll
        for (int s = 0; s < 4; s++)
            afrag[s] = __builtin_bit_cast(bf16x8, *(const int4*)(A + s * 32));
    } else {
        const float* A = (const float*)Aptr + (size_t)arc * 128 + kb * 8;
#pragma unroll
        for (int s = 0; s < 4; s++) {
            float4 v0 = *(const float4*)(A + s * 32);
            float4 v1 = *(const float4*)(A + s * 32 + 4);
            bf16x8 t;
            t[0] = (bf16_t)v0.x; t[1] = (bf16_t)v0.y;
            t[2] = (bf16_t)v0.z; t[3] = (bf16_t)v0.w;
            t[4] = (bf16_t)v1.x; t[5] = (bf16_t)v1.y;
            t[6] = (bf16_t)v1.z; t[7] = (bf16_t)v1.w;
            afrag[s] = t;
        }
    }

#pragma unroll
    for (int ct = 0; ct < 8; ct++) acc[ct] = (f32x4){0.f, 0.f, 0.f, 0.f};

#pragma unroll
    for (int ct = 0; ct < 8; ct++) {
#pragma unroll
        for (int s = 0; s < 4; s++) {
            bf16x8 bfrag = __builtin_bit_cast(
                bf16x8, *(const int4*)(wf + (((ct << 2) + s) << 9) + (lane << 3)));
            acc[ct] = __builtin_amdgcn_mfma_f32_16x16x32_bf16(
                afrag[s], bfrag, acc[ct], 0, 0, 0);
        }
    }
}

// Epilogue: bias + relu (+ optional BN affine), store bf16.
// C/D layout (m89-verified): col = lane&15, row = (lane>>4)*4 + j
template <bool BN>
__device__ __forceinline__ void gemm_epi_store(
    f32x4 acc[8], const float* __restrict__ bias,
    const float* __restrict__ gamma, const float* __restrict__ beta,
    const float* __restrict__ mmean, const float* __restrict__ mvar,
    u16* __restrict__ obf, int M, int row0, int lane)
{
    const int crow0 = row0 + ((lane >> 4) << 2);
    const int ccol  = lane & 15;
#pragma unroll
    for (int ct = 0; ct < 8; ct++) {
        int col  = (ct << 4) + ccol;
        float b  = bias[col];
        float scale = 1.f, shift = 0.f;
        if (BN) {
            float s_ = gamma[col] / sqrtf(mvar[col] + 1e-3f);
            scale = s_;
            shift = beta[col] - mmean[col] * s_;
        }
#pragma unroll
        for (int j = 0; j < 4; j++) {
            int row = crow0 + j;
            if (row < M) {
                float v = fmaxf(acc[ct][j] + b, 0.f);
                if (BN) v = v * scale + shift;
                obf[(size_t)row * 128 + col] = __builtin_bit_cast(u16, (bf16_t)v);
            }
        }
    }
}

// Block-local exclusive scan of bsum[0..nb) into sb (nb <= 256).
__device__ __forceinline__ void scan_bsum(
    const int* __restrict__ bsum, int nb, int* sb)
{
    int v = (threadIdx.x < (unsigned)nb) ? bsum[threadIdx.x] : 0;
    sb[threadIdx.x] = v;
    __syncthreads();
    for (int off = 1; off < 256; off <<= 1) {
        int t = (threadIdx.x >= (unsigned)off) ? sb[threadIdx.x - off] : 0;
        __syncthreads();
        sb[threadIdx.x] += t;
        __syncthreads();
    }
    int inc = sb[threadIdx.x];
    __syncthreads();
    sb[threadIdx.x] = inc - v;          // exclusive
    __syncthreads();
}

// Deep-batched CSR neighbor gather: up to 8 independent row loads in flight.
__device__ __forceinline__ void gather_node(
    const u16* __restrict__ t, const int* __restrict__ csr,
    int beg, int end, int c8, float acc[8])
{
    int i = beg;
    while (i + 8 <= end) {
        int idx[8];
#pragma unroll
        for (int u = 0; u < 8; u++) idx[u] = csr[i + u];
        int4 rows[8];
#pragma unroll
        for (int u = 0; u < 8; u++)
            rows[u] = *(const int4*)(t + (size_t)idx[u] * 128 + c8);
#pragma unroll
        for (int u = 0; u < 8; u++) {
            bf16x8 v = __builtin_bit_cast(bf16x8, rows[u]);
#pragma unroll
            for (int j = 0; j < 8; j++) acc[j] += (float)v[j];
        }
        i += 8;
    }
    if (i + 4 <= end) {
        int idx[4];
#pragma unroll
        for (int u = 0; u < 4; u++) idx[u] = csr[i + u];
        int4 rows[4];
#pragma unroll
        for (int u = 0; u < 4; u++)
            rows[u] = *(const int4*)(t + (size_t)idx[u] * 128 + c8);
#pragma unroll
        for (int u = 0; u < 4; u++) {
            bf16x8 v = __builtin_bit_cast(bf16x8, rows[u]);
#pragma unroll
            for (int j = 0; j < 8; j++) acc[j] += (float)v[j];
        }
        i += 4;
    }
    for (; i < end; ++i) {
        int src = csr[i];
        bf16x8 v = __builtin_bit_cast(bf16x8,
            *(const int4*)(t + (size_t)src * 128 + c8));
#pragma unroll
        for (int j = 0; j < 8; j++) acc[j] += (float)v[j];
    }
}

// ---------------------------------------------------------------------------
// Dispatch A: zero (deg, cur, out)  ||  weight-fragment pre-pack.
// ---------------------------------------------------------------------------
__global__ __launch_bounds__(256) void fusedA(
    const float* __restrict__ W1, const float* __restrict__ W2,
    const float* __restrict__ W3, const float* __restrict__ W4,
    u16* __restrict__ wf, int* __restrict__ deg, int* __restrict__ cur,
    float* __restrict__ out, int N, int outsz, int nb)
{
    if ((int)blockIdx.x < nb) {
        int i = blockIdx.x * 256 + threadIdx.x;
        if (i < N) { deg[i] = 0; cur[i] = 0; }
        if (i < outsz) out[i] = 0.f;
    } else {
        int idx = (blockIdx.x - nb) * 256 + threadIdx.x;   // 0..65535
        const float* Ws[4] = {W1, W2, W3, W4};
        int w  = idx >> 14;
        int e  = idx & 16383;
        int i  = e & 7;
        int l  = (e >> 3) & 63;
        int s  = (e >> 9) & 3;
        int ct = (e >> 11) & 7;
        int row = 32 * s + 8 * (l >> 4) + i;
        int col = 16 * ct + (l & 15);
        float v = Ws[w][row * 128 + col];
        wf[idx] = __builtin_bit_cast(u16, (bf16_t)v);
    }
}

// ---------------------------------------------------------------------------
// Dispatch B: GEMM1 (x f32 -> h1 bf16, BN1)  ||  degree histogram.
// ---------------------------------------------------------------------------
__global__ __launch_bounds__(256) void fusedB(
    const float* __restrict__ x, const u16* __restrict__ wf,
    const float* __restrict__ b1, const float* __restrict__ g1,
    const float* __restrict__ be1, const float* __restrict__ mm1,
    const float* __restrict__ mv1, u16* __restrict__ h1, int M,
    const int* __restrict__ ei, int* __restrict__ deg, int E, int gb)
{
    if ((int)blockIdx.x < gb) {
        int lane = threadIdx.x & 63, wv = threadIdx.x >> 6;
        int row0 = (blockIdx.x * 4 + wv) * 16;
        f32x4 acc[8];
        gemm_core<false>(x, wf, M, row0, lane, acc);
        gemm_epi_store<true>(acc, b1, g1, be1, mm1, mv1, h1, M, row0, lane);
    } else {
        int e = (blockIdx.x - gb) * 256 + threadIdx.x;
        if (e < E) {
            int2 p = ((const int2*)ei)[e];
            atomicAdd(&deg[p.y], 1);
        }
    }
}

// ---------------------------------------------------------------------------
// Dispatch C: GEMM2 (h1 -> tb, no BN)  ||  scan1 (block-local exclusive scan
// of deg into rs, block sums into bsum).
// ---------------------------------------------------------------------------
__global__ __launch_bounds__(256) void fusedC(
    const u16* __restrict__ h1, const u16* __restrict__ wf,
    const float* __restrict__ b2, u16* __restrict__ tb, int M,
    const int* __restrict__ deg, int* __restrict__ rs, int* __restrict__ bsum,
    int N, int gb)
{
    if ((int)blockIdx.x < gb) {
        int lane = threadIdx.x & 63, wv = threadIdx.x >> 6;
        int row0 = (blockIdx.x * 4 + wv) * 16;
        f32x4 acc[8];
        gemm_core<true>(h1, wf, M, row0, lane, acc);
        gemm_epi_store<false>(acc, b2, nullptr, nullptr, nullptr, nullptr,
                              tb, M, row0, lane);
    } else {
        __shared__ int sh[256];
        int blk = blockIdx.x - gb;
        int i = blk * 256 + threadIdx.x;
        int v = (i < N) ? deg[i] : 0;
        sh[threadIdx.x] = v;
        __syncthreads();
        for (int off = 1; off < 256; off <<= 1) {
            int t = (threadIdx.x >= (unsigned)off) ? sh[threadIdx.x - off] : 0;
            __syncthreads();
            sh[threadIdx.x] += t;
            __syncthreads();
        }
        if (i < N) rs[i] = sh[threadIdx.x] - v;          // block-local exclusive
        if (threadIdx.x == 255) bsum[blk] = sh[255];
    }
}

// ---------------------------------------------------------------------------
// Dispatch D: scatter edges into CSR slots; blocks < nb also materialize
// absolute row starts rsa[i] = rs[i] + sb[i>>8] (so consumers skip the scan).
// ---------------------------------------------------------------------------
__global__ __launch_bounds__(256) void scatterk(
    const int* __restrict__ ei, const int* __restrict__ rs,
    const int* __restrict__ bsum, int* __restrict__ cur,
    int* __restrict__ csr, int* __restrict__ rsa, int E, int N, int nb)
{
    __shared__ int sb[256];
    scan_bsum(bsum, nb, sb);

    if ((int)blockIdx.x < nb) {
        int i = blockIdx.x * 256 + threadIdx.x;
        if (i < N) rsa[i] = rs[i] + sb[i >> 8];
        if (blockIdx.x == 0 && threadIdx.x == 0) rsa[N] = E;
    }

    int e = blockIdx.x * 256 + threadIdx.x;
    if (e < E) {
        int2 p = ((const int2*)ei)[e];
        int slot = atomicAdd(&cur[p.y], 1);
        csr[rs[p.y] + sb[p.y >> 8] + slot] = p.x;
    }
}

// ---------------------------------------------------------------------------
// Dispatches E/F: fused GIN-aggregate + GEMM.
// Phase 1: block gathers its 64 rows' neighborhoods (self + CSR neighbors,
//   8-deep batched loads) into an XOR-swizzled LDS A-tile:
//   byte = rl*256 + ((c ^ (rl&7)) << 4)  (2-way bank aliasing = free, m136).
// Phase 2: MFMA from LDS.
// Epilogue: BN store (E) or LDS-staged group reduction (F).
// ---------------------------------------------------------------------------
template <bool BN_, bool RED>
__global__ __launch_bounds__(256) void aggGemm(
    const u16* __restrict__ t, const int* __restrict__ rsa,
    const int* __restrict__ csr,
    const u16* __restrict__ wf, const float* __restrict__ bias,
    const float* __restrict__ gamma, const float* __restrict__ beta,
    const float* __restrict__ mmean, const float* __restrict__ mvar,
    u16* __restrict__ obf, const int* __restrict__ batch,
    float* __restrict__ out, int N, int E)
{
    constexpr int GSPAN = 20;
    __shared__ u16 ldsA[64 * 128];
    __shared__ float grp[RED ? (GSPAN * 128) : 1];

    const int row0blk = blockIdx.x * 64;
    const int sub = threadIdx.x >> 4;       // 0..15: node within pass
    const int c   = threadIdx.x & 15;       // 16B chunk within row
    const int c8  = c << 3;

#pragma unroll
    for (int pass = 0; pass < 4; pass++) {
        int rl   = pass * 16 + sub;         // 0..63 local row
        int node = row0blk + rl;
        float acc[8];
        if (node < N) {
            bf16x8 s8 = __builtin_bit_cast(
                bf16x8, *(const int4*)(t + (size_t)node * 128 + c8));
#pragma unroll
            for (int j = 0; j < 8; j++) acc[j] = (float)s8[j];
            gather_node(t, csr, rsa[node], rsa[node + 1], c8, acc);
        } else {
#pragma unroll
            for (int j = 0; j < 8; j++) acc[j] = 0.f;
        }
        bf16x8 o;
#pragma unroll
        for (int j = 0; j < 8; j++) o[j] = (bf16_t)acc[j];
        *(int4*)((char*)ldsA + rl * 256 + ((c ^ (rl & 7)) << 4)) =
            __builtin_bit_cast(int4, o);
    }

    if (RED) {
        for (int i = threadIdx.x; i < GSPAN * 128; i += 256) grp[i] = 0.f;
    }
    __syncthreads();

    // ---- GEMM from swizzled LDS ----
    const int lane = threadIdx.x & 63;
    const int wv   = threadIdx.x >> 6;
    const int r    = lane & 15;
    const int kb   = lane >> 4;
    const int rl   = wv * 16 + r;

    bf16x8 afrag[4];
#pragma unroll
    for (int s = 0; s < 4; s++)
        afrag[s] = __builtin_bit_cast(
            bf16x8, *(const int4*)((const char*)ldsA + rl * 256 +
                                   ((((s << 2) + kb) ^ (rl & 7)) << 4)));

    f32x4 acc[8];
#pragma unroll
    for (int ct = 0; ct < 8; ct++) acc[ct] = (f32x4){0.f, 0.f, 0.f, 0.f};
#pragma unroll
    for (int ct = 0; ct < 8; ct++) {
#pragma unroll
        for (int s = 0; s < 4; s++) {
            bf16x8 bfrag = __builtin_bit_cast(
                bf16x8, *(const int4*)(wf + (((ct << 2) + s) << 9) + (lane << 3)));
            acc[ct] = __builtin_amdgcn_mfma_f32_16x16x32_bf16(
                afrag[s], bfrag, acc[ct], 0, 0, 0);
        }
    }

    const int row0 = row0blk + wv * 16;
    if constexpr (!RED) {
        gemm_epi_store<BN_>(acc, bias, gamma, beta, mmean, mvar, obf, N, row0, lane);
    } else {
        int gfirst = batch[row0blk];
        int lastr  = row0blk + 63 < N - 1 ? row0blk + 63 : N - 1;
        int glast  = batch[lastr];
        const int crow0 = row0 + ((lane >> 4) << 2);
        const int ccol  = lane & 15;
        int bj[4];
#pragma unroll
        for (int j = 0; j < 4; j++) {
            int row = crow0 + j;
            bj[j] = (row < N) ? batch[row] : -1;
        }
        if (glast - gfirst < GSPAN) {
#pragma unroll
            for (int ct = 0; ct < 8; ct++) {
                int col = (ct << 4) + ccol;
                float b = bias[col];
                float run = 0.f;
                int gp = -1;
#pragma unroll
                for (int j = 0; j < 4; j++) {
                    if (bj[j] < 0) continue;
                    float v = fmaxf(acc[ct][j] + b, 0.f);
                    if (bj[j] != gp) {
                        if (gp >= 0) atomicAdd(&grp[(gp - gfirst) * 128 + col], run);
                        run = 0.f;
                        gp  = bj[j];
                    }
                    run += v;
                }
                if (gp >= 0) atomicAdd(&grp[(gp - gfirst) * 128 + col], run);
            }
            __syncthreads();
            int span = glast - gfirst + 1;
            for (int i = threadIdx.x; i < span * 128; i += 256) {
                float v = grp[i];
                if (v != 0.f) atomicAdd(out + (size_t)gfirst * 128 + i, v);
            }
        } else {
            // pathological tiny-group fallback: direct global atomics
#pragma unroll
            for (int ct = 0; ct < 8; ct++) {
                int col = (ct << 4) + ccol;
                float b = bias[col];
                float run = 0.f;
                int gp = -1;
#pragma unroll
                for (int j = 0; j < 4; j++) {
                    if (bj[j] < 0) continue;
                    float v = fmaxf(acc[ct][j] + b, 0.f);
                    if (bj[j] != gp) {
                        if (gp >= 0) atomicAdd(out + (size_t)gp * 128 + col, run);
                        run = 0.f;
                        gp  = bj[j];
                    }
                    run += v;
                }
                if (gp >= 0) atomicAdd(out + (size_t)gp * 128 + col, run);
            }
        }
    }
}

// ---------------------------------------------------------------------------
static inline size_t al256(size_t x) { return (x + 255) & ~(size_t)255; }

extern "C" void kernel_launch(void* const* d_in, const int* in_sizes, int n_in,
                              void* d_out, int out_size, void* d_ws, size_t ws_size,
                              hipStream_t stream)
{
    const float* x   = (const float*)d_in[0];
    const int*   ei  = (const int*)d_in[1];
    const int*   bat = (const int*)d_in[2];
    const float* W1  = (const float*)d_in[3];
    const float* b1  = (const float*)d_in[4];
    const float* g1  = (const float*)d_in[5];
    const float* be1 = (const float*)d_in[6];
    const float* mm1 = (const float*)d_in[7];
    const float* mv1 = (const float*)d_in[8];
    const float* W2  = (const float*)d_in[9];
    const float* b2  = (const float*)d_in[10];
    const float* W3  = (const float*)d_in[11];
    const float* b3  = (const float*)d_in[12];
    const float* g2  = (const float*)d_in[13];
    const float* be2 = (const float*)d_in[14];
    const float* mm2 = (const float*)d_in[15];
    const float* mv2 = (const float*)d_in[16];
    const float* W4  = (const float*)d_in[17];
    const float* b4  = (const float*)d_in[18];
    float* out = (float*)d_out;

    const int N  = in_sizes[0] / 128;
    const int E  = in_sizes[1] / 2;
    const int nb = (N + 255) / 256;
    const int eb = (E + 255) / 256;
    const int gb = (N + 63) / 64;

    char* ws = (char*)d_ws;
    size_t off = 0;
    u16*   wf   = (u16*)(ws + off);  off += al256(4 * 16384 * sizeof(u16));
    u16*   h1   = (u16*)(ws + off);  off += al256((size_t)N * 128 * sizeof(u16));
    u16*   tb   = (u16*)(ws + off);  off += al256((size_t)N * 128 * sizeof(u16));
    int*   rs   = (int*)(ws + off);  off += al256((size_t)N * sizeof(int));
    int*   rsa  = (int*)(ws + off);  off += al256((size_t)(N + 1) * sizeof(int));
    int*   deg  = (int*)(ws + off);  off += al256((size_t)N * sizeof(int));
    int*   cur  = (int*)(ws + off);  off += al256((size_t)N * sizeof(int));
    int*   bsum = (int*)(ws + off);  off += al256((size_t)nb * sizeof(int));
    int*   csr  = (int*)(ws + off);  off += al256((size_t)E * sizeof(int));

    // A: zero(deg,cur,out) || wfrag pack
    fusedA<<<nb + 256, 256, 0, stream>>>(W1, W2, W3, W4, wf, deg, cur, out,
                                         N, out_size, nb);
    // B: GEMM1 || hist
    fusedB<<<gb + eb, 256, 0, stream>>>(x, wf, b1, g1, be1, mm1, mv1, h1, N,
                                        ei, deg, E, gb);
    // C: GEMM2 || scan1
    fusedC<<<gb + nb, 256, 0, stream>>>(h1, wf + 16384, b2, tb, N,
                                        deg, rs, bsum, N, gb);
    // D: scatter into CSR + materialize rsa
    scatterk<<<eb, 256, 0, stream>>>(ei, rs, bsum, cur, csr, rsa, E, N, nb);
    // E: h1 = bn2(relu( (tb + gather(tb)) @ W3 + b3 ))
    aggGemm<true, false><<<gb, 256, 0, stream>>>(
        tb, rsa, csr, wf + 2 * 16384, b3, g2, be2, mm2, mv2,
        h1, nullptr, nullptr, N, E);
    // F: out += group-reduce relu( (h1 + gather(h1)) @ W4 + b4 )
    aggGemm<false, true><<<gb, 256, 0, stream>>>(
        h1, rsa, csr, wf + 3 * 16384, b4, nullptr, nullptr, nullptr, nullptr,
        nullptr, bat, out, N, E);
}

// Round 7
// 167.749 us; speedup vs baseline: 3.9066x; 1.0226x over previous
//
#include <hip/hip_runtime.h>
#include <hip/hip_bf16.h>

typedef unsigned short u16;
typedef __bf16 bf16_t;
typedef bf16_t bf16x8 __attribute__((ext_vector_type(8)));
typedef float f32x4 __attribute__((ext_vector_type(4)));

// NOTE: csr entries are u16 node ids — requires N < 65536 (problem: N=50000).

// ---------------------------------------------------------------------------
// GEMM core (global A): one wave computes 16 rows x 128 cols of
// A[M,128] @ W[128,128] via 8 col-tiles x 4 k-steps of mfma_f32_16x16x32_bf16.
// B-fragments from prepacked wf (16B/lane contiguous). Same intra-lane k map
// for A and B, so any HW k-permutation cancels.
// ---------------------------------------------------------------------------
template <bool ABF16>
__device__ __forceinline__ void gemm_core(
    const void* __restrict__ Aptr, const u16* __restrict__ wf,
    int M, int row0, int lane, f32x4 acc[8])
{
    const int r  = lane & 15;
    const int kb = lane >> 4;
    int arow = row0 + r;
    int arc  = arow < M ? arow : (M - 1);

    bf16x8 afrag[4];
    if (ABF16) {
        const u16* A = (const u16*)Aptr + (size_t)arc * 128 + kb * 8;
#pragma unroll
        for (int s = 0; s < 4; s++)
            afrag[s] = __builtin_bit_cast(bf16x8, *(const int4*)(A + s * 32));
    } else {
        const float* A = (const float*)Aptr + (size_t)arc * 128 + kb * 8;
#pragma unroll
        for (int s = 0; s < 4; s++) {
            float4 v0 = *(const float4*)(A + s * 32);
            float4 v1 = *(const float4*)(A + s * 32 + 4);
            bf16x8 t;
            t[0] = (bf16_t)v0.x; t[1] = (bf16_t)v0.y;
            t[2] = (bf16_t)v0.z; t[3] = (bf16_t)v0.w;
            t[4] = (bf16_t)v1.x; t[5] = (bf16_t)v1.y;
            t[6] = (bf16_t)v1.z; t[7] = (bf16_t)v1.w;
            afrag[s] = t;
        }
    }

#pragma unroll
    for (int ct = 0; ct < 8; ct++) acc[ct] = (f32x4){0.f, 0.f, 0.f, 0.f};

#pragma unroll
    for (int ct = 0; ct < 8; ct++) {
#pragma unroll
        for (int s = 0; s < 4; s++) {
            bf16x8 bfrag = __builtin_bit_cast(
                bf16x8, *(const int4*)(wf + (((ct << 2) + s) << 9) + (lane << 3)));
            acc[ct] = __builtin_amdgcn_mfma_f32_16x16x32_bf16(
                afrag[s], bfrag, acc[ct], 0, 0, 0);
        }
    }
}

// Epilogue: bias + relu (+ optional BN affine), store bf16.
// C/D layout (m89-verified): col = lane&15, row = (lane>>4)*4 + j
template <bool BN>
__device__ __forceinline__ void gemm_epi_store(
    f32x4 acc[8], const float* __restrict__ bias,
    const float* __restrict__ gamma, const float* __restrict__ beta,
    const float* __restrict__ mmean, const float* __restrict__ mvar,
    u16* __restrict__ obf, int M, int row0, int lane)
{
    const int crow0 = row0 + ((lane >> 4) << 2);
    const int ccol  = lane & 15;
#pragma unroll
    for (int ct = 0; ct < 8; ct++) {
        int col  = (ct << 4) + ccol;
        float b  = bias[col];
        float scale = 1.f, shift = 0.f;
        if (BN) {
            float s_ = gamma[col] / sqrtf(mvar[col] + 1e-3f);
            scale = s_;
            shift = beta[col] - mmean[col] * s_;
        }
#pragma unroll
        for (int j = 0; j < 4; j++) {
            int row = crow0 + j;
            if (row < M) {
                float v = fmaxf(acc[ct][j] + b, 0.f);
                if (BN) v = v * scale + shift;
                obf[(size_t)row * 128 + col] = __builtin_bit_cast(u16, (bf16_t)v);
            }
        }
    }
}

// Block-local exclusive scan of bsum[0..nb) into sb (nb <= 256).
__device__ __forceinline__ void scan_bsum(
    const int* __restrict__ bsum, int nb, int* sb)
{
    int v = (threadIdx.x < (unsigned)nb) ? bsum[threadIdx.x] : 0;
    sb[threadIdx.x] = v;
    __syncthreads();
    for (int off = 1; off < 256; off <<= 1) {
        int t = (threadIdx.x >= (unsigned)off) ? sb[threadIdx.x - off] : 0;
        __syncthreads();
        sb[threadIdx.x] += t;
        __syncthreads();
    }
    int inc = sb[threadIdx.x];
    __syncthreads();
    sb[threadIdx.x] = inc - v;          // exclusive
    __syncthreads();
}

// Deep-batched CSR neighbor gather: up to 8 independent row loads in flight.
__device__ __forceinline__ void gather_node(
    const u16* __restrict__ t, const u16* __restrict__ csr,
    int beg, int end, int c8, float acc[8])
{
    int i = beg;
    while (i + 8 <= end) {
        int idx[8];
#pragma unroll
        for (int u = 0; u < 8; u++) idx[u] = csr[i + u];
        int4 rows[8];
#pragma unroll
        for (int u = 0; u < 8; u++)
            rows[u] = *(const int4*)(t + (size_t)idx[u] * 128 + c8);
#pragma unroll
        for (int u = 0; u < 8; u++) {
            bf16x8 v = __builtin_bit_cast(bf16x8, rows[u]);
#pragma unroll
            for (int j = 0; j < 8; j++) acc[j] += (float)v[j];
        }
        i += 8;
    }
    if (i + 4 <= end) {
        int idx[4];
#pragma unroll
        for (int u = 0; u < 4; u++) idx[u] = csr[i + u];
        int4 rows[4];
#pragma unroll
        for (int u = 0; u < 4; u++)
            rows[u] = *(const int4*)(t + (size_t)idx[u] * 128 + c8);
#pragma unroll
        for (int u = 0; u < 4; u++) {
            bf16x8 v = __builtin_bit_cast(bf16x8, rows[u]);
#pragma unroll
            for (int j = 0; j < 8; j++) acc[j] += (float)v[j];
        }
        i += 4;
    }
    for (; i < end; ++i) {
        int src = csr[i];
        bf16x8 v = __builtin_bit_cast(bf16x8,
            *(const int4*)(t + (size_t)src * 128 + c8));
#pragma unroll
        for (int j = 0; j < 8; j++) acc[j] += (float)v[j];
    }
}

// ---------------------------------------------------------------------------
// Dispatch Z: zero deg and out.
// ---------------------------------------------------------------------------
__global__ __launch_bounds__(256) void zerok(
    int* __restrict__ deg, float* __restrict__ out, int N, int outsz)
{
    int i = blockIdx.x * 256 + threadIdx.x;
    if (i < N) deg[i] = 0;
    if (i < outsz) out[i] = 0.f;
}

// ---------------------------------------------------------------------------
// Dispatch A: weight-fragment pre-pack || degree histogram.
// ---------------------------------------------------------------------------
__global__ __launch_bounds__(256) void fusedA(
    const float* __restrict__ W1, const float* __restrict__ W2,
    const float* __restrict__ W3, const float* __restrict__ W4,
    u16* __restrict__ wf, const int* __restrict__ ei,
    int* __restrict__ deg, int E)
{
    if (blockIdx.x < 256) {
        int idx = blockIdx.x * 256 + threadIdx.x;          // 0..65535
        const float* Ws[4] = {W1, W2, W3, W4};
        int w  = idx >> 14;
        int e  = idx & 16383;
        int i  = e & 7;
        int l  = (e >> 3) & 63;
        int s  = (e >> 9) & 3;
        int ct = (e >> 11) & 7;
        int row = 32 * s + 8 * (l >> 4) + i;
        int col = 16 * ct + (l & 15);
        float v = Ws[w][row * 128 + col];
        wf[idx] = __builtin_bit_cast(u16, (bf16_t)v);
    } else {
        int e = (blockIdx.x - 256) * 256 + threadIdx.x;
        if (e < E) {
            int2 p = ((const int2*)ei)[e];
            atomicAdd(&deg[p.y], 1);
        }
    }
}

// ---------------------------------------------------------------------------
// Dispatch B: GEMM1 (x f32 -> h1 bf16, BN1)  ||  scan1 (deg -> rs, bsum).
// ---------------------------------------------------------------------------
__global__ __launch_bounds__(256) void fusedB(
    const float* __restrict__ x, const u16* __restrict__ wf,
    const float* __restrict__ b1, const float* __restrict__ g1,
    const float* __restrict__ be1, const float* __restrict__ mm1,
    const float* __restrict__ mv1, u16* __restrict__ h1, int M,
    const int* __restrict__ deg, int* __restrict__ rs, int* __restrict__ bsum,
    int N, int gb)
{
    if ((int)blockIdx.x < gb) {
        int lane = threadIdx.x & 63, wv = threadIdx.x >> 6;
        int row0 = (blockIdx.x * 4 + wv) * 16;
        f32x4 acc[8];
        gemm_core<false>(x, wf, M, row0, lane, acc);
        gemm_epi_store<true>(acc, b1, g1, be1, mm1, mv1, h1, M, row0, lane);
    } else {
        __shared__ int sh[256];
        int blk = blockIdx.x - gb;
        int i = blk * 256 + threadIdx.x;
        int v = (i < N) ? deg[i] : 0;
        sh[threadIdx.x] = v;
        __syncthreads();
        for (int off = 1; off < 256; off <<= 1) {
            int t = (threadIdx.x >= (unsigned)off) ? sh[threadIdx.x - off] : 0;
            __syncthreads();
            sh[threadIdx.x] += t;
            __syncthreads();
        }
        if (i < N) rs[i] = sh[threadIdx.x] - v;          // block-local exclusive
        if (threadIdx.x == 255) bsum[blk] = sh[255];
    }
}

// ---------------------------------------------------------------------------
// Dispatch C: GEMM2 (h1 -> tb, no BN)  ||  scatter edges into u16 CSR slots
// (+ materialize absolute row starts rsa). slot comes from counting deg back
// down with atomicSub (deg is dead after scan1).
// ---------------------------------------------------------------------------
__global__ __launch_bounds__(256) void fusedC(
    const u16* __restrict__ h1, const u16* __restrict__ wf,
    const float* __restrict__ b2, u16* __restrict__ tb, int M,
    const int* __restrict__ ei, const int* __restrict__ rs,
    const int* __restrict__ bsum, int* __restrict__ deg,
    u16* __restrict__ csr, int* __restrict__ rsa,
    int E, int N, int nb, int gb)
{
    if ((int)blockIdx.x < gb) {
        int lane = threadIdx.x & 63, wv = threadIdx.x >> 6;
        int row0 = (blockIdx.x * 4 + wv) * 16;
        f32x4 acc[8];
        gemm_core<true>(h1, wf, M, row0, lane, acc);
        gemm_epi_store<false>(acc, b2, nullptr, nullptr, nullptr, nullptr,
                              tb, M, row0, lane);
    } else {
        __shared__ int sb[256];
        scan_bsum(bsum, nb, sb);
        int blk = blockIdx.x - gb;

        if (blk < nb) {
            int i = blk * 256 + threadIdx.x;
            if (i < N) rsa[i] = rs[i] + sb[i >> 8];
            if (blk == 0 && threadIdx.x == 0) rsa[N] = E;
        }

        int e = blk * 256 + threadIdx.x;
        if (e < E) {
            int2 p = ((const int2*)ei)[e];
            int slot = atomicSub(&deg[p.y], 1) - 1;
            csr[rs[p.y] + sb[p.y >> 8] + slot] = (u16)p.x;
        }
    }
}

// ---------------------------------------------------------------------------
// Dispatches D/E: fused GIN-aggregate + GEMM.
// Phase 1: block gathers its 64 rows' neighborhoods (self + CSR neighbors,
//   8-deep batched loads) into an XOR-swizzled LDS A-tile:
//   byte = rl*256 + ((c ^ (rl&7)) << 4)  (2-way bank aliasing = free, m136).
// Phase 2: MFMA from LDS.
// Epilogue: BN store (D) or LDS-staged group reduction (E).
// ---------------------------------------------------------------------------
template <bool BN_, bool RED>
__global__ __launch_bounds__(256) void aggGemm(
    const u16* __restrict__ t, const int* __restrict__ rsa,
    const u16* __restrict__ csr,
    const u16* __restrict__ wf, const float* __restrict__ bias,
    const float* __restrict__ gamma, const float* __restrict__ beta,
    const float* __restrict__ mmean, const float* __restrict__ mvar,
    u16* __restrict__ obf, const int* __restrict__ batch,
    float* __restrict__ out, int N, int E)
{
    constexpr int GSPAN = 20;
    __shared__ u16 ldsA[64 * 128];
    __shared__ float grp[RED ? (GSPAN * 128) : 1];

    const int row0blk = blockIdx.x * 64;
    const int sub = threadIdx.x >> 4;       // 0..15: node within pass
    const int c   = threadIdx.x & 15;       // 16B chunk within row
    const int c8  = c << 3;

#pragma unroll
    for (int pass = 0; pass < 4; pass++) {
        int rl   = pass * 16 + sub;         // 0..63 local row
        int node = row0blk + rl;
        float acc[8];
        if (node < N) {
            bf16x8 s8 = __builtin_bit_cast(
                bf16x8, *(const int4*)(t + (size_t)node * 128 + c8));
#pragma unroll
            for (int j = 0; j < 8; j++) acc[j] = (float)s8[j];
            gather_node(t, csr, rsa[node], rsa[node + 1], c8, acc);
        } else {
#pragma unroll
            for (int j = 0; j < 8; j++) acc[j] = 0.f;
        }
        bf16x8 o;
#pragma unroll
        for (int j = 0; j < 8; j++) o[j] = (bf16_t)acc[j];
        *(int4*)((char*)ldsA + rl * 256 + ((c ^ (rl & 7)) << 4)) =
            __builtin_bit_cast(int4, o);
    }

    if (RED) {
        for (int i = threadIdx.x; i < GSPAN * 128; i += 256) grp[i] = 0.f;
    }
    __syncthreads();

    // ---- GEMM from swizzled LDS ----
    const int lane = threadIdx.x & 63;
    const int wv   = threadIdx.x >> 6;
    const int r    = lane & 15;
    const int kb   = lane >> 4;
    const int rl   = wv * 16 + r;

    bf16x8 afrag[4];
#pragma unroll
    for (int s = 0; s < 4; s++)
        afrag[s] = __builtin_bit_cast(
            bf16x8, *(const int4*)((const char*)ldsA + rl * 256 +
                                   ((((s << 2) + kb) ^ (rl & 7)) << 4)));

    f32x4 acc[8];
#pragma unroll
    for (int ct = 0; ct < 8; ct++) acc[ct] = (f32x4){0.f, 0.f, 0.f, 0.f};
#pragma unroll
    for (int ct = 0; ct < 8; ct++) {
#pragma unroll
        for (int s = 0; s < 4; s++) {
            bf16x8 bfrag = __builtin_bit_cast(
                bf16x8, *(const int4*)(wf + (((ct << 2) + s) << 9) + (lane << 3)));
            acc[ct] = __builtin_amdgcn_mfma_f32_16x16x32_bf16(
                afrag[s], bfrag, acc[ct], 0, 0, 0);
        }
    }

    const int row0 = row0blk + wv * 16;
    if constexpr (!RED) {
        gemm_epi_store<BN_>(acc, bias, gamma, beta, mmean, mvar, obf, N, row0, lane);
    } else {
        int gfirst = batch[row0blk];
        int lastr  = row0blk + 63 < N - 1 ? row0blk + 63 : N - 1;
        int glast  = batch[lastr];
        const int crow0 = row0 + ((lane >> 4) << 2);
        const int ccol  = lane & 15;
        int bj[4];
#pragma unroll
        for (int j = 0; j < 4; j++) {
            int row = crow0 + j;
            bj[j] = (row < N) ? batch[row] : -1;
        }
        if (glast - gfirst < GSPAN) {
#pragma unroll
            for (int ct = 0; ct < 8; ct++) {
                int col = (ct << 4) + ccol;
                float b = bias[col];
                float run = 0.f;
                int gp = -1;
#pragma unroll
                for (int j = 0; j < 4; j++) {
                    if (bj[j] < 0) continue;
                    float v = fmaxf(acc[ct][j] + b, 0.f);
                    if (bj[j] != gp) {
                        if (gp >= 0) atomicAdd(&grp[(gp - gfirst) * 128 + col], run);
                        run = 0.f;
                        gp  = bj[j];
                    }
                    run += v;
                }
                if (gp >= 0) atomicAdd(&grp[(gp - gfirst) * 128 + col], run);
            }
            __syncthreads();
            int span = glast - gfirst + 1;
            for (int i = threadIdx.x; i < span * 128; i += 256) {
                float v = grp[i];
                if (v != 0.f) atomicAdd(out + (size_t)gfirst * 128 + i, v);
            }
        } else {
            // pathological tiny-group fallback: direct global atomics
#pragma unroll
            for (int ct = 0; ct < 8; ct++) {
                int col = (ct << 4) + ccol;
                float b = bias[col];
                float run = 0.f;
                int gp = -1;
#pragma unroll
                for (int j = 0; j < 4; j++) {
                    if (bj[j] < 0) continue;
                    float v = fmaxf(acc[ct][j] + b, 0.f);
                    if (bj[j] != gp) {
                        if (gp >= 0) atomicAdd(out + (size_t)gp * 128 + col, run);
                        run = 0.f;
                        gp  = bj[j];
                    }
                    run += v;
                }
                if (gp >= 0) atomicAdd(out + (size_t)gp * 128 + col, run);
            }
        }
    }
}

// ---------------------------------------------------------------------------
static inline size_t al256(size_t x) { return (x + 255) & ~(size_t)255; }

extern "C" void kernel_launch(void* const* d_in, const int* in_sizes, int n_in,
                              void* d_out, int out_size, void* d_ws, size_t ws_size,
                              hipStream_t stream)
{
    const float* x   = (const float*)d_in[0];
    const int*   ei  = (const int*)d_in[1];
    const int*   bat = (const int*)d_in[2];
    const float* W1  = (const float*)d_in[3];
    const float* b1  = (const float*)d_in[4];
    const float* g1  = (const float*)d_in[5];
    const float* be1 = (const float*)d_in[6];
    const float* mm1 = (const float*)d_in[7];
    const float* mv1 = (const float*)d_in[8];
    const float* W2  = (const float*)d_in[9];
    const float* b2  = (const float*)d_in[10];
    const float* W3  = (const float*)d_in[11];
    const float* b3  = (const float*)d_in[12];
    const float* g2  = (const float*)d_in[13];
    const float* be2 = (const float*)d_in[14];
    const float* mm2 = (const float*)d_in[15];
    const float* mv2 = (const float*)d_in[16];
    const float* W4  = (const float*)d_in[17];
    const float* b4  = (const float*)d_in[18];
    float* out = (float*)d_out;

    const int N  = in_sizes[0] / 128;
    const int E  = in_sizes[1] / 2;
    const int nb = (N + 255) / 256;
    const int eb = (E + 255) / 256;
    const int gb = (N + 63) / 64;

    char* ws = (char*)d_ws;
    size_t off = 0;
    u16*   wf   = (u16*)(ws + off);  off += al256(4 * 16384 * sizeof(u16));
    u16*   h1   = (u16*)(ws + off);  off += al256((size_t)N * 128 * sizeof(u16));
    u16*   tb   = (u16*)(ws + off);  off += al256((size_t)N * 128 * sizeof(u16));
    int*   rs   = (int*)(ws + off);  off += al256((size_t)N * sizeof(int));
    int*   rsa  = (int*)(ws + off);  off += al256((size_t)(N + 1) * sizeof(int));
    int*   deg  = (int*)(ws + off);  off += al256((size_t)N * sizeof(int));
    int*   bsum = (int*)(ws + off);  off += al256((size_t)nb * sizeof(int));
    u16*   csr  = (u16*)(ws + off);  off += al256((size_t)E * sizeof(u16));

    // Z: zero deg, out
    zerok<<<nb, 256, 0, stream>>>(deg, out, N, out_size);
    // A: wfrag pack || hist
    fusedA<<<256 + eb, 256, 0, stream>>>(W1, W2, W3, W4, wf, ei, deg, E);
    // B: GEMM1 || scan1
    fusedB<<<gb + nb, 256, 0, stream>>>(x, wf, b1, g1, be1, mm1, mv1, h1, N,
                                        deg, rs, bsum, N, gb);
    // C: GEMM2 || scatter(u16) + rsa
    fusedC<<<gb + eb, 256, 0, stream>>>(h1, wf + 16384, b2, tb, N,
                                        ei, rs, bsum, deg, csr, rsa,
                                        E, N, nb, gb);
    // D: h1 = bn2(relu( (tb + gather(tb)) @ W3 + b3 ))
    aggGemm<true, false><<<gb, 256, 0, stream>>>(
        tb, rsa, csr, wf + 2 * 16384, b3, g2, be2, mm2, mv2,
        h1, nullptr, nullptr, N, E);
    // E: out += group-reduce relu( (h1 + gather(h1)) @ W4 + b4 )
    aggGemm<false, true><<<gb, 256, 0, stream>>>(
        h1, rsa, csr, wf + 3 * 16384, b4, nullptr, nullptr, nullptr, nullptr,
        nullptr, bat, out, N, E);
}